// Round 2
// baseline (565.587 us; speedup 1.0000x reference)
//
#include <hip/hip_runtime.h>
#include <hip/hip_bf16.h>

#define FFT_PI 3.14159265358979323846f
#define FOFF(i) ((i) + ((i) >> 3))   // padded LDS offset for row FFTs
#define CSW(r, c) ((c) ^ ((r) & 15)) // col-FFT LDS bank swizzle (bijective/row)

typedef __hip_bfloat16 bf16;
typedef short bf8_t __attribute__((ext_vector_type(8)));
typedef float f4_t __attribute__((ext_vector_type(4)));

__device__ inline float bf2f(unsigned short u) {
    union { unsigned int i; float f; } v; v.i = ((unsigned int)u) << 16; return v.f;
}
__device__ inline unsigned short f2bf(float f) {
    bf16 h = __float2bfloat16(f);
    union { bf16 h; unsigned short u; } v; v.h = h; return v.u;
}
__device__ inline float2 c_load(const ushort2* p) {
    ushort2 u = *p;
    return make_float2(bf2f(u.x), bf2f(u.y));
}
__device__ inline int brev6(int t) {
    return ((t & 1) << 5) | ((t & 2) << 3) | ((t & 4) << 1) |
           ((t & 8) >> 1) | ((t & 16) >> 3) | ((t & 32) >> 5);
}
__device__ inline float2 cadd(float2 a, float2 b){ return make_float2(a.x+b.x, a.y+b.y); }
__device__ inline float2 csub(float2 a, float2 b){ return make_float2(a.x-b.x, a.y-b.y); }
__device__ inline float2 cmul(float2 a, float2 b){
    return make_float2(a.x*b.x - a.y*b.y, a.x*b.y + a.y*b.x);
}
__device__ inline float2 cmuli(float2 a, float s){ return make_float2(-s*a.y, s*a.x); }

// async global->LDS, 16 B per lane; LDS dest = base + lane*16 (HW contract)
__device__ inline void async_load16(const void* gp, void* lp) {
    __builtin_amdgcn_global_load_lds(
        (const __attribute__((address_space(1))) void*)gp,
        (__attribute__((address_space(3))) void*)lp, 16, 0, 0);
}

// ---------------------------------------------------------------------------
// Merged transpose+convert for all 7 weights.
// ---------------------------------------------------------------------------
__global__ __launch_bounds__(256) void transpose_cvt_all(
    const float* __restrict__ s0, const float* __restrict__ s1,
    const float* __restrict__ s2, const float* __restrict__ s3,
    const float* __restrict__ s4, const float* __restrict__ s5,
    const float* __restrict__ s6, bf16* __restrict__ Wt)
{
    const int z = blockIdx.z;
    const int R = (z == 6) ? 1024 : 512;
    if (blockIdx.y * 32 >= R) return;
    const float* src = (z == 0) ? s0 : (z == 1) ? s1 : (z == 2) ? s2 :
                       (z == 3) ? s3 : (z == 4) ? s4 : (z == 5) ? s5 : s6;
    bf16* dst = Wt + (long)z * 262144;
    const int C = 512;

    __shared__ float tile[32][33];
    const int bx = blockIdx.x * 32;
    const int by = blockIdx.y * 32;
    const int tx = threadIdx.x, ty = threadIdx.y;
#pragma unroll
    for (int i = 0; i < 32; i += 8)
        tile[ty + i][tx] = src[(long)(by + ty + i) * C + bx + tx];
    __syncthreads();
#pragma unroll
    for (int i = 0; i < 32; i += 8)
        dst[(long)(bx + ty + i) * R + by + tx] = __float2bfloat16(tile[tx][ty + i]);
}

// ---------------------------------------------------------------------------
// MFMA bf16 GEMM v2: tile 128x128, BK=32, 4 waves. Unpadded LDS [128][32]
// shorts; global_load_lds width-16 staging for bf16 A (a_type 0) and all B.
// a_type: 0 = bf16 [m][k] (async), 1 = f32 [m][k] (manual convert).
// Two A buffers via ksplit. Multi-output via nper/sel. out_type as before.
// ---------------------------------------------------------------------------
__global__ __launch_bounds__(256) void mfma_gemm(
    const void* __restrict__ Av, const void* __restrict__ Av2,
    int a_type, int lda, int ksplit,
    const bf16* __restrict__ Bt, int ldb,
    const float* __restrict__ bias0, const float* __restrict__ bias1,
    const float* __restrict__ bias2,
    void* __restrict__ C0, void* __restrict__ C1, void* __restrict__ C2,
    int nper, int out_type, int ldc, int K,
    const float* __restrict__ e0, const float* __restrict__ e1,
    const float* __restrict__ e2, const float* __restrict__ e3)
{
    __shared__ short Asub[128 * 32];   // unpadded, 8 KB
    __shared__ short Bsub[128 * 32];

    const int tid = threadIdx.x;
    const int n0 = blockIdx.x * 128;
    const int m0 = blockIdx.y * 128;
    const int l  = tid & 63;
    const int wv = tid >> 6;
    const int wm = wv & 1, wn = wv >> 1;

    f4_t acc[4][4];
#pragma unroll
    for (int i = 0; i < 4; i++)
#pragma unroll
        for (int j = 0; j < 4; j++)
            acc[i][j] = (f4_t)0.f;

    const int crow = l >> 2;        // row within 16-row chunk
    const int cpc  = (l & 3) * 8;   // k-piece (shorts)

    for (int k0 = 0; k0 < K; k0 += 32) {
        const void* As = (k0 < ksplit) ? Av : Av2;
        const int kk = (k0 < ksplit) ? k0 : (k0 - ksplit);

        if (a_type == 0) {
#pragma unroll
            for (int c = 0; c < 2; c++) {
                const int chunk = wv * 2 + c;
                const int row = chunk * 16 + crow;
                async_load16((const bf16*)As + (long)(m0 + row) * lda + kk + cpc,
                             &Asub[chunk * 512]);
                async_load16(Bt + (long)(n0 + row) * ldb + k0 + cpc,
                             &Bsub[chunk * 512]);
            }
        } else {
            // manual f32 -> bf16 staging (conv2 GEMM only)
            const int srow = tid >> 2;
            const int sc8  = (tid & 3) * 8;
#pragma unroll
            for (int p = 0; p < 2; p++) {
                const int row = srow + p * 64;
                const float4* src = (const float4*)((const float*)As
                    + (long)(m0 + row) * lda + kk + sc8);
                float4 u0 = src[0], u1 = src[1];
                bf8_t av;
                av[0] = (short)f2bf(u0.x); av[1] = (short)f2bf(u0.y);
                av[2] = (short)f2bf(u0.z); av[3] = (short)f2bf(u0.w);
                av[4] = (short)f2bf(u1.x); av[5] = (short)f2bf(u1.y);
                av[6] = (short)f2bf(u1.z); av[7] = (short)f2bf(u1.w);
                *(bf8_t*)&Asub[row * 32 + sc8] = av;
            }
#pragma unroll
            for (int c = 0; c < 2; c++) {
                const int chunk = wv * 2 + c;
                const int row = chunk * 16 + crow;
                async_load16(Bt + (long)(n0 + row) * ldb + k0 + cpc,
                             &Bsub[chunk * 512]);
            }
        }
        __syncthreads();

        bf8_t a_frag[4], b_frag[4];
        const int ko = (l >> 4) * 8;
        const int lr = l & 15;
#pragma unroll
        for (int fm = 0; fm < 4; fm++)
            a_frag[fm] = *(bf8_t*)&Asub[(wm * 64 + fm * 16 + lr) * 32 + ko];
#pragma unroll
        for (int fn = 0; fn < 4; fn++)
            b_frag[fn] = *(bf8_t*)&Bsub[(wn * 64 + fn * 16 + lr) * 32 + ko];
#pragma unroll
        for (int fm = 0; fm < 4; fm++)
#pragma unroll
            for (int fn = 0; fn < 4; fn++)
                acc[fm][fn] = __builtin_amdgcn_mfma_f32_16x16x32_bf16(
                    b_frag[fn], a_frag[fm], acc[fm][fn], 0, 0, 0);
        __syncthreads();
    }

    const int sel = n0 / nper;
    const int nb  = sel * nper;
    const float* biasl = (sel == 0) ? bias0 : ((sel == 1) ? bias1 : bias2);
    void* Cl = (sel == 0) ? C0 : ((sel == 1) ? C1 : C2);

    const int em = m0 + wm * 64 + (l & 15);
    const int en = n0 + wn * 64 + ((l >> 4) << 2);
#pragma unroll
    for (int fm = 0; fm < 4; fm++) {
        const long m = em + fm * 16;
        float bnm = 0.f, bnr = 1.f, bng = 1.f, bnb = 0.f;
        if (out_type == 3) {
            const int c = (int)(m & 511);
            bnm = e0[c];
            bnr = 1.0f / sqrtf(e1[c] + 1e-5f);
            bng = e2[c];
            bnb = e3[c];
        }
#pragma unroll
        for (int fn = 0; fn < 4; fn++) {
            const int n = en + fn * 16;
            const int nl = n - nb;
            f4_t v = acc[fm][fn];
            if (biasl) {
#pragma unroll
                for (int r = 0; r < 4; r++) v[r] += biasl[nl + r];
            }
            if (out_type == 0) {
                float4 o; o.x = v[0]; o.y = v[1]; o.z = v[2]; o.w = v[3];
                *(float4*)((float*)Cl + m * ldc + nl) = o;
            } else if (out_type == 1) {
                union { unsigned short u[4]; ushort4 q; } o;
#pragma unroll
                for (int r = 0; r < 4; r++) o.u[r] = f2bf(v[r]);
                *(ushort4*)((bf16*)Cl + m * ldc + nl) = o.q;
            } else if (out_type == 2) {
                union { ushort2 u2[4]; uint4 q; } o;
#pragma unroll
                for (int r = 0; r < 4; r++) { o.u2[r].x = f2bf(v[r]); o.u2[r].y = 0; }
                *(uint4*)((ushort2*)Cl + m * ldc + nl) = o.q;
            } else if (out_type == 3) {
                union { unsigned short u[4]; ushort4 q; } o;
#pragma unroll
                for (int r = 0; r < 4; r++)
                    o.u[r] = f2bf(fmaxf((v[r] - bnm) * bnr * bng + bnb, 0.f));
                *(ushort4*)((bf16*)Cl + m * ldc + nl) = o.q;
            } else {
                union { unsigned short u[4]; ushort4 q; } rsd;
                rsd.q = *(const ushort4*)((const unsigned short*)e0 + m * ldc + nl);
                float4 o;
                o.x = v[0] + bf2f(rsd.u[0]);
                o.y = v[1] + bf2f(rsd.u[1]);
                o.z = v[2] + bf2f(rsd.u[2]);
                o.w = v[3] + bf2f(rsd.u[3]);
                *(float4*)((float*)Cl + m * ldc + nl) = o;
            }
        }
    }
}

// ---------------------------------------------------------------------------
// Radix-8 512-point Stockham FFT (two-buffer, row kernels).
// ---------------------------------------------------------------------------
__device__ inline void dft8(float2* x, float sgn)
{
    const float c45 = 0.70710678118654752f;
    float2 e0, e1, e2, e3, o0, o1, o2, o3;
    {
        float2 u0 = cadd(x[0], x[4]), u1 = csub(x[0], x[4]);
        float2 u2 = cadd(x[2], x[6]), u3 = cmuli(csub(x[2], x[6]), sgn);
        e0 = cadd(u0, u2); e1 = cadd(u1, u3); e2 = csub(u0, u2); e3 = csub(u1, u3);
    }
    {
        float2 u0 = cadd(x[1], x[5]), u1 = csub(x[1], x[5]);
        float2 u2 = cadd(x[3], x[7]), u3 = cmuli(csub(x[3], x[7]), sgn);
        o0 = cadd(u0, u2); o1 = cadd(u1, u3); o2 = csub(u0, u2); o3 = csub(u1, u3);
    }
    const float2 w1 = make_float2(c45, sgn * c45);
    const float2 w3 = make_float2(-c45, sgn * c45);
    o1 = cmul(o1, w1);
    o2 = cmuli(o2, sgn);
    o3 = cmul(o3, w3);
    x[0] = cadd(e0, o0); x[4] = csub(e0, o0);
    x[1] = cadd(e1, o1); x[5] = csub(e1, o1);
    x[2] = cadd(e2, o2); x[6] = csub(e2, o2);
    x[3] = cadd(e3, o3); x[7] = csub(e3, o3);
}

__device__ inline void fft512_r8(float2* bx0, float2* by0, int lane, float sign)
{
    float2* bx = bx0;
    float2* by = by0;
#pragma unroll
    for (int st = 0; st < 3; st++) {
        int n, m, sstr, p, q;
        if (st == 0)      { n = 512; m = 64; sstr = 1;  p = lane;      q = 0; }
        else if (st == 1) { n = 64;  m = 8;  sstr = 8;  p = lane >> 3; q = lane & 7; }
        else              { n = 8;   m = 1;  sstr = 64; p = 0;         q = lane; }
        float2 x[8];
#pragma unroll
        for (int r = 0; r < 8; r++) x[r] = bx[FOFF(q + sstr * (p + r * m))];
        dft8(x, sign);
        if (p) {
            float ang = sign * (2.0f * FFT_PI) * (float)p / (float)n;
            float sw, cw;
            __sincosf(ang, &sw, &cw);
            float2 w = make_float2(cw, sw), wk = w;
#pragma unroll
            for (int k = 1; k < 8; k++) { x[k] = cmul(x[k], wk); wk = cmul(wk, w); }
        }
#pragma unroll
        for (int k = 0; k < 8; k++) by[FOFF(q + sstr * (8 * p + k))] = x[k];
        __syncthreads();
        float2* t = bx; bx = by; by = t;
    }
}

// All forward row FFTs in one dispatch: buf 0..2 = Q/K/V c2c in-place;
// buf 3 = r2c conv2 -> Tb. 4 lines/block.
__global__ __launch_bounds__(256) void fft8_rows_all(
    ushort2* __restrict__ qkv, const bf16* __restrict__ conv2,
    ushort2* __restrict__ tb)
{
    __shared__ float2 B0[4][576], B1[4][576];
    const int buf = blockIdx.x >> 12;
    const int lb  = blockIdx.x & 4095;
    const int li = threadIdx.x >> 6, lane = threadIdx.x & 63;
    const long line = (long)lb * 4 + li;

    if (buf < 3) {
        ushort2* s = qkv + (long)buf * 8388608 + line * 512;
        uint4 r0 = *(const uint4*)(s + lane * 8);
        uint4 r1 = *(const uint4*)(s + lane * 8 + 4);
        float2* dst = &B0[li][9 * lane];
        const ushort2* pp = (const ushort2*)&r0;
#pragma unroll
        for (int j = 0; j < 4; j++) dst[j] = c_load(pp + j);
        pp = (const ushort2*)&r1;
#pragma unroll
        for (int j = 0; j < 4; j++) dst[4 + j] = c_load(pp + j);
        __syncthreads();
        fft512_r8(B0[li], B1[li], lane, -1.f);
        float2* src = &B1[li][9 * lane];
        union { ushort2 u[4]; uint4 q; } o0, o1;
#pragma unroll
        for (int j = 0; j < 4; j++) {
            float2 z = src[j]; o0.u[j].x = f2bf(z.x); o0.u[j].y = f2bf(z.y);
        }
#pragma unroll
        for (int j = 0; j < 4; j++) {
            float2 z = src[4 + j]; o1.u[j].x = f2bf(z.x); o1.u[j].y = f2bf(z.y);
        }
        *(uint4*)(s + lane * 8) = o0.q;
        *(uint4*)(s + lane * 8 + 4) = o1.q;
    } else {
        uint4 raw = *(const uint4*)((const unsigned short*)conv2 + line * 512 + lane * 8);
        const unsigned short* pp = (const unsigned short*)&raw;
        float2* d = &B0[li][9 * lane];
#pragma unroll
        for (int j = 0; j < 8; j++) d[j] = make_float2(bf2f(pp[j]), 0.f);
        __syncthreads();
        fft512_r8(B0[li], B1[li], lane, -1.f);
        ushort2* s = tb + line * 512;
        float2* src = &B1[li][9 * lane];
        union { ushort2 u[4]; uint4 q; } o0, o1;
#pragma unroll
        for (int j = 0; j < 4; j++) {
            float2 z = src[j]; o0.u[j].x = f2bf(z.x); o0.u[j].y = f2bf(z.y);
        }
#pragma unroll
        for (int j = 0; j < 4; j++) {
            float2 z = src[4 + j]; o1.u[j].x = f2bf(z.x); o1.u[j].y = f2bf(z.y);
        }
        *(uint4*)(s + lane * 8) = o0.q;
        *(uint4*)(s + lane * 8 + 4) = o1.q;
    }
}

// gated row inverse FFT: sigmoid(g2)*tep, ifft, scale 1/512, in place
__global__ __launch_bounds__(256) void fft8_rows_gated(
    const bf16* __restrict__ g2, ushort2* __restrict__ tep)
{
    __shared__ float2 B0[4][576], B1[4][576];
    const int li = threadIdx.x >> 6, lane = threadIdx.x & 63;
    const long line = (long)blockIdx.x * 4 + li;
    ushort2* s = tep + line * 512;
    {
        uint4 rg = *(const uint4*)((const unsigned short*)g2 + line * 512 + lane * 8);
        uint4 r0 = *(const uint4*)(s + lane * 8);
        uint4 r1 = *(const uint4*)(s + lane * 8 + 4);
        const unsigned short* gp = (const unsigned short*)&rg;
        float2* d = &B0[li][9 * lane];
        const ushort2* pp = (const ushort2*)&r0;
#pragma unroll
        for (int j = 0; j < 4; j++) {
            float sg = 1.0f / (1.0f + __expf(-bf2f(gp[j])));
            float2 z = c_load(pp + j);
            d[j] = make_float2(sg * z.x, sg * z.y);
        }
        pp = (const ushort2*)&r1;
#pragma unroll
        for (int j = 0; j < 4; j++) {
            float sg = 1.0f / (1.0f + __expf(-bf2f(gp[4 + j])));
            float2 z = c_load(pp + j);
            d[4 + j] = make_float2(sg * z.x, sg * z.y);
        }
    }
    __syncthreads();
    fft512_r8(B0[li], B1[li], lane, +1.f);
    {
        const float sc = 1.0f / 512.0f;
        float2* src = &B1[li][9 * lane];
        union { ushort2 u[4]; uint4 q; } o0, o1;
#pragma unroll
        for (int j = 0; j < 4; j++) {
            float2 z = src[j];
            o0.u[j].x = f2bf(z.x * sc); o0.u[j].y = f2bf(z.y * sc);
        }
#pragma unroll
        for (int j = 0; j < 4; j++) {
            float2 z = src[4 + j];
            o1.u[j].x = f2bf(z.x * sc); o1.u[j].y = f2bf(z.y * sc);
        }
        *(uint4*)(s + lane * 8) = o0.q;
        *(uint4*)(s + lane * 8 + 4) = o1.q;
    }
}

// ---------------------------------------------------------------------------
// Column FFT: 16 columns/block, single 64 KB LDS, in-place stages (verified
// R9). Fused over 4 buffers (Q/K/V/T); buf==3 writes real parts to tepReal.
// LDS col index XOR-swizzled with (row&15): [512][16] f2 has row stride
// 32 words == 0 mod 32 banks, so bank = f(col) only; unswizzled staging/
// output phases were 16-way conflicts (3.1M SQ_LDS_BANK_CONFLICT). The
// swizzle gives the optimal even 4-phase b64 distribution in every phase.
// ---------------------------------------------------------------------------
__global__ __launch_bounds__(256) void fft8_cols16_c2c4(
    ushort2* __restrict__ data, bf16* __restrict__ tepReal, float sign)
{
    __shared__ float2 B[512][16];
    const int buf = blockIdx.x >> 10;
    const int rem = blockIdx.x & 1023;
    const int b   = rem >> 5;
    const int c0  = (rem & 31) * 16;
    ushort2* base = data + (long)buf * 8388608 + (long)b * 262144 + c0;
    const int t = threadIdx.x;
    const int lr = t >> 2;
    const int lq = t & 3;

#pragma unroll
    for (int it = 0; it < 8; it++) {
        const int row = it * 64 + lr;
        uint4 raw = *(const uint4*)(base + (long)row * 512 + lq * 4);
        const ushort2* pp = (const ushort2*)&raw;
#pragma unroll
        for (int j = 0; j < 4; j++) B[row][CSW(row, lq * 4 + j)] = c_load(pp + j);
    }
    __syncthreads();

    const int col = t & 15;
    const int rb  = t >> 4;
#pragma unroll
    for (int st = 0; st < 3; st++) {
        int n, m, s;
        if (st == 0)      { n = 512; m = 64; s = 1;  }
        else if (st == 1) { n = 64;  m = 8;  s = 8;  }
        else              { n = 8;   m = 1;  s = 64; }
        float2 x[4][8];
        int ps[4], qs[4];
#pragma unroll
        for (int i = 0; i < 4; i++) {
            const int role = rb + 16 * i;
            int p, q;
            if (st == 0)      { p = role;      q = 0; }
            else if (st == 1) { p = role >> 3; q = role & 7; }
            else              { p = 0;         q = role; }
            ps[i] = p; qs[i] = q;
#pragma unroll
            for (int r = 0; r < 8; r++) {
                const int rr = q + s * (p + r * m);
                x[i][r] = B[rr][CSW(rr, col)];
            }
        }
        __syncthreads();
#pragma unroll
        for (int i = 0; i < 4; i++) {
            dft8(x[i], sign);
            const int p = ps[i];
            if (p) {
                float ang = sign * (2.0f * FFT_PI) * (float)p / (float)n;
                float sw, cw;
                __sincosf(ang, &sw, &cw);
                float2 w = make_float2(cw, sw), wk = w;
#pragma unroll
                for (int k = 1; k < 8; k++) { x[i][k] = cmul(x[i][k], wk); wk = cmul(wk, w); }
            }
#pragma unroll
            for (int k = 0; k < 8; k++) {
                const int rw = qs[i] + s * (8 * p + k);
                B[rw][CSW(rw, col)] = x[i][k];
            }
        }
        __syncthreads();
    }

#pragma unroll
    for (int it = 0; it < 8; it++) {
        const int row = it * 64 + lr;
        union { ushort2 u[4]; uint4 q4; } o;
        union { unsigned short u[4]; ushort4 q4; } orl;
#pragma unroll
        for (int j = 0; j < 4; j++) {
            float2 z = B[row][CSW(row, lq * 4 + j)];
            o.u[j].x = f2bf(z.x); o.u[j].y = f2bf(z.y);
            orl.u[j] = o.u[j].x;
        }
        *(uint4*)(base + (long)row * 512 + lq * 4) = o.q4;
        if (buf == 3)
            *(ushort4*)(tepReal + (long)b * 262144 + (long)row * 512 + c0 + lq * 4) = orl.q4;
    }
}

// Column inverse FFT + abs -> bf16 real (scale 1/512), 16 columns/block.
__global__ __launch_bounds__(256) void fft8_cols16_abs(
    const ushort2* __restrict__ src, bf16* __restrict__ dst)
{
    __shared__ float2 B[512][16];
    const int b  = blockIdx.x >> 5;
    const int c0 = (blockIdx.x & 31) * 16;
    const ushort2* base = src + (long)b * 262144 + c0;
    const int t = threadIdx.x;
    const int lr = t >> 2;
    const int lq = t & 3;

#pragma unroll
    for (int it = 0; it < 8; it++) {
        const int row = it * 64 + lr;
        uint4 raw = *(const uint4*)(base + (long)row * 512 + lq * 4);
        const ushort2* pp = (const ushort2*)&raw;
#pragma unroll
        for (int j = 0; j < 4; j++) B[row][CSW(row, lq * 4 + j)] = c_load(pp + j);
    }
    __syncthreads();

    const int col = t & 15;
    const int rb  = t >> 4;
#pragma unroll
    for (int st = 0; st < 3; st++) {
        int n, m, s;
        if (st == 0)      { n = 512; m = 64; s = 1;  }
        else if (st == 1) { n = 64;  m = 8;  s = 8;  }
        else              { n = 8;   m = 1;  s = 64; }
        float2 x[4][8];
        int ps[4], qs[4];
#pragma unroll
        for (int i = 0; i < 4; i++) {
            const int role = rb + 16 * i;
            int p, q;
            if (st == 0)      { p = role;      q = 0; }
            else if (st == 1) { p = role >> 3; q = role & 7; }
            else              { p = 0;         q = role; }
            ps[i] = p; qs[i] = q;
#pragma unroll
            for (int r = 0; r < 8; r++) {
                const int rr = q + s * (p + r * m);
                x[i][r] = B[rr][CSW(rr, col)];
            }
        }
        __syncthreads();
#pragma unroll
        for (int i = 0; i < 4; i++) {
            dft8(x[i], +1.f);
            const int p = ps[i];
            if (p) {
                float ang = (2.0f * FFT_PI) * (float)p / (float)n;
                float sw, cw;
                __sincosf(ang, &sw, &cw);
                float2 w = make_float2(cw, sw), wk = w;
#pragma unroll
                for (int k = 1; k < 8; k++) { x[i][k] = cmul(x[i][k], wk); wk = cmul(wk, w); }
            }
#pragma unroll
            for (int k = 0; k < 8; k++) {
                const int rw = qs[i] + s * (8 * p + k);
                B[rw][CSW(rw, col)] = x[i][k];
            }
        }
        __syncthreads();
    }

    const float sc = 1.0f / 512.0f;
#pragma unroll
    for (int it = 0; it < 8; it++) {
        const int row = it * 64 + lr;
        union { unsigned short u[4]; ushort4 q4; } o;
#pragma unroll
        for (int j = 0; j < 4; j++) {
            float2 z = B[row][CSW(row, lq * 4 + j)];
            o.u[j] = f2bf(sqrtf(z.x * z.x + z.y * z.y) * sc);
        }
        *(ushort4*)(dst + (long)b * 262144 + (long)row * 512 + c0 + lq * 4) = o.q4;
    }
}

// ---------------------------------------------------------------------------
// attn v4: 4 (b,c) per block; raw bf16 LDS staging (no pre-normalize pass —
// norms folded into the score loop), LDS ~19.7 KB -> 8 blocks/CU.
// Row pad 68 complex: 272 B stride keeps uint4 alignment and spreads the 8
// head-rows over banks 4h..4h+3 (conflict-free broadcast reads).
// ---------------------------------------------------------------------------
__global__ __launch_bounds__(256) void attn_kernel(
    const ushort2* __restrict__ qf, const ushort2* __restrict__ kf,
    const ushort2* __restrict__ vf, const float* __restrict__ temp,
    bf16* __restrict__ out_f)
{
    __shared__ ushort2 QS[4][8][68];   // raw bf16 q rows
    __shared__ ushort2 KS[4][8][68];   // raw bf16 k rows
    __shared__ float2 ATT[4][8][9];

    const int li = threadIdx.x >> 6, lane = threadIdx.x & 63;
    const int bc = blockIdx.x * 4 + li;
    const long base = (long)bc * 512;

    // stage raw bf16 q,k rows: 2x uint4 (4 complex) per lane per buffer
    {
        const int h1 = lane >> 4, w1 = (lane & 15) * 4;
        uint4 q0 = *(const uint4*)(qf + base + lane * 4);
        uint4 q1 = *(const uint4*)(qf + base + 256 + lane * 4);
        uint4 k0 = *(const uint4*)(kf + base + lane * 4);
        uint4 k1 = *(const uint4*)(kf + base + 256 + lane * 4);
        *(uint4*)&QS[li][h1][w1]     = q0;
        *(uint4*)&QS[li][h1 + 4][w1] = q1;
        *(uint4*)&KS[li][h1][w1]     = k0;
        *(uint4*)&KS[li][h1 + 4][w1] = k1;
    }
    float2 v[8];
#pragma unroll
    for (int h = 0; h < 8; h++)
        v[h] = c_load(vf + base + h * 64 + lane);
    __syncthreads();

    // scores + norms + softmax, fully parallel: lane = (h = lane>>3, g = lane&7)
    // score[h][g] = (q_h . k_g) * temp[h] / (|q_h| |k_g|)  ==  normalized dot
    {
        const int h = lane >> 3, g = lane & 7;
        float ar = 0.f, ai = 0.f, nq = 0.f, nk = 0.f;
#pragma unroll
        for (int w = 0; w < 64; w += 4) {
            uint4 qa = *(const uint4*)&QS[li][h][w];
            uint4 kb = *(const uint4*)&KS[li][g][w];
            const unsigned short* qs = (const unsigned short*)&qa;
            const unsigned short* ks = (const unsigned short*)&kb;
#pragma unroll
            for (int j = 0; j < 4; j++) {
                float qx = bf2f(qs[2 * j]), qy = bf2f(qs[2 * j + 1]);
                float kx = bf2f(ks[2 * j]), ky = bf2f(ks[2 * j + 1]);
                ar += qx * kx - qy * ky;
                ai += qx * ky + qy * kx;
                nq += qx * qx + qy * qy;
                nk += kx * kx + ky * ky;
            }
        }
        const float iq = 1.0f / fmaxf(sqrtf(nq), 1e-12f);
        const float ik = 1.0f / fmaxf(sqrtf(nk), 1e-12f);
        const float s = temp[h] * iq * ik;
        ar *= s; ai *= s;
        // group-of-8 max (offsets 1,2,4 stay within the h-group)
        float mr = ar, mi = ai;
#pragma unroll
        for (int o = 1; o < 8; o <<= 1) {
            mr = fmaxf(mr, __shfl_xor(mr, o, 64));
            mi = fmaxf(mi, __shfl_xor(mi, o, 64));
        }
        float er = __expf(ar - mr), ei = __expf(ai - mi);
        float sr = er, si = ei;
#pragma unroll
        for (int o = 1; o < 8; o <<= 1) {
            sr += __shfl_xor(sr, o, 64);
            si += __shfl_xor(si, o, 64);
        }
        ATT[li][h][g] = make_float2(er / sr, ei / si);
    }
    __syncthreads();

    float2 o[8];
#pragma unroll
    for (int h = 0; h < 8; h++) {
        float orr = 0.f, oi = 0.f;
#pragma unroll
        for (int g = 0; g < 8; g++) {
            float2 a = ATT[li][h][g], b = v[g];
            orr += a.x * b.x - a.y * b.y;
            oi  += a.x * b.y + a.y * b.x;
        }
        o[h] = make_float2(orr, oi);
    }

#pragma unroll
    for (int m = 32; m >= 1; m >>= 1) {
        float ang = (FFT_PI / (float)m) * (float)(lane & (m - 1));
        float sw, cw;
        __sincosf(ang, &sw, &cw);
        const bool low = (lane & m) == 0;
#pragma unroll
        for (int h = 0; h < 8; h++) {
            float px = __shfl_xor(o[h].x, m, 64);
            float py = __shfl_xor(o[h].y, m, 64);
            float nx, ny;
            if (low) {
                nx = o[h].x + px;
                ny = o[h].y + py;
            } else {
                float dx = px - o[h].x;
                float dy = py - o[h].y;
                nx = dx * cw - dy * sw;
                ny = dx * sw + dy * cw;
            }
            o[h].x = nx; o[h].y = ny;
        }
    }
    const int wr = brev6(lane);

    const float r2 = 0.70710678118654752f;
    const float W8x[8] = {1.f,  r2, 0.f, -r2, -1.f, -r2,  0.f,  r2};
    const float W8y[8] = {0.f,  r2, 1.f,  r2,  0.f, -r2, -1.f, -r2};
    unsigned short* stg = (unsigned short*)&QS[li][0][0];
#pragma unroll
    for (int kh = 0; kh < 8; kh++) {
        float sr = 0.f, si = 0.f;
#pragma unroll
        for (int n = 0; n < 8; n++) {
            const int idx = (n * kh) & 7;
            float wx = W8x[idx], wy = W8y[idx];
            sr += o[n].x * wx - o[n].y * wy;
            si += o[n].x * wy + o[n].y * wx;
        }
        stg[kh * 64 + wr] = f2bf(sqrtf(sr * sr + si * si) * (1.0f / 512.0f));
    }
    __syncthreads();
    uint4 ov = *(uint4*)(stg + lane * 8);
    *(uint4*)((unsigned short*)out_f + base + lane * 8) = ov;
}

// ---------------------------------------------------------------------------
extern "C" void kernel_launch(void* const* d_in, const int* in_sizes, int n_in,
                              void* d_out, int out_size, void* d_ws, size_t ws_size,
                              hipStream_t stream)
{
    const float* x     = (const float*)d_in[0];
    const float* W_in  = (const float*)d_in[1];
    const float* b_in  = (const float*)d_in[2];
    const float* W_q   = (const float*)d_in[3];
    const float* b_q   = (const float*)d_in[4];
    const float* W_k   = (const float*)d_in[5];
    const float* b_k   = (const float*)d_in[6];
    const float* W_v   = (const float*)d_in[7];
    const float* b_v   = (const float*)d_in[8];
    const float* temp  = (const float*)d_in[9];
    const float* W1a   = (const float*)d_in[10];
    const float* b1a   = (const float*)d_in[11];
    const float* gam   = (const float*)d_in[12];
    const float* bet   = (const float*)d_in[13];
    const float* mea   = (const float*)d_in[14];
    const float* var   = (const float*)d_in[15];
    const float* W1b   = (const float*)d_in[16];
    const float* b1b   = (const float*)d_in[17];
    const float* W_out = (const float*)d_in[18];
    const float* b_out = (const float*)d_in[19];

    char* wsb = (char*)d_ws;
    const long MB = 1024 * 1024;
    bf16*    conv2b  = (bf16*)wsb;
    bf16*    tepReal = (bf16*)(wsb + 16 * MB);
    ushort2* Qb    = (ushort2*)(wsb + 32 * MB);
    ushort2* Kb    = (ushort2*)(wsb + 64 * MB);
    ushort2* Vb    = (ushort2*)(wsb + 96 * MB);
    ushort2* Tb    = (ushort2*)(wsb + 128 * MB);
    bf16*    Wt    = (bf16*)(wsb + 160 * MB);
    bf16* WT_in  = Wt;
    bf16* WT_q   = Wt + 262144;
    bf16* WT_1a  = Wt + 4 * 262144;
    bf16* WT_1b  = Wt + 5 * 262144;
    bf16* WT_out = Wt + 6 * 262144;
    bf16* outF = (bf16*)Qb;
    bf16* g1b  = (bf16*)Kb;
    bf16* outL = (bf16*)Kb;
    bf16* g2b  = (bf16*)Vb;

    const dim3 ggrid(4, 128), gblk(256);
    const int BIG = 1 << 30;
    const int RB = 4096;

    transpose_cvt_all<<<dim3(16, 32, 7), dim3(32, 8), 0, stream>>>(
        W_in, W_q, W_k, W_v, W1a, W1b, W_out, Wt);

    // 1. conv2 = x @ W_in + b_in -> bf16  (f32 A, manual staging)
    mfma_gemm<<<ggrid, gblk, 0, stream>>>(
        x, x, 1, 512, BIG, WT_in, 512, b_in, nullptr, nullptr,
        conv2b, nullptr, nullptr, BIG, 1, 512, 512,
        nullptr, nullptr, nullptr, nullptr);

    // 2. fused q/k/v projections (async staging)
    mfma_gemm<<<dim3(12, 128), gblk, 0, stream>>>(
        conv2b, conv2b, 0, 512, BIG, WT_q, 512, b_q, b_k, b_v,
        Qb, Kb, Vb, 512, 2, 512, 512,
        nullptr, nullptr, nullptr, nullptr);

    // 3. all row FFTs (Q/K/V c2c + tep r2c) in one dispatch
    fft8_rows_all<<<4 * RB, 256, 0, stream>>>(Qb, conv2b, Tb);

    // 4. col FFTs: Q,K,V,T fused, 16 cols/block (+ tepReal side output)
    fft8_cols16_c2c4<<<4096, 256, 0, stream>>>(Qb, tepReal, -1.f);

    // 5. attention -> out_f bf16 over Qb
    attn_kernel<<<RB, 256, 0, stream>>>(Qb, Kb, Vb, temp, outF);

    // 6. g1 = BN_ReLU(tepReal @ W1a + b1a) -> bf16
    mfma_gemm<<<ggrid, gblk, 0, stream>>>(
        tepReal, tepReal, 0, 512, BIG, WT_1a, 512, b1a, nullptr, nullptr,
        g1b, nullptr, nullptr, BIG, 3, 512, 512,
        mea, var, gam, bet);

    // 7. g2 = g1 @ W1b + b1b -> bf16
    mfma_gemm<<<ggrid, gblk, 0, stream>>>(
        g1b, g1b, 0, 512, BIG, WT_1b, 512, b1b, nullptr, nullptr,
        g2b, nullptr, nullptr, BIG, 1, 512, 512,
        nullptr, nullptr, nullptr, nullptr);

    // 8. gated ifft2 + abs -> out_l bf16 (over Kb)
    fft8_rows_gated<<<RB, 256, 0, stream>>>(g2b, Tb);
    fft8_cols16_abs<<<1024, 256, 0, stream>>>(Tb, outL);

    // 9. d_out = [out_f | out_l] @ W_out + b_out + conv2 (K=1024, fused residual)
    mfma_gemm<<<ggrid, gblk, 0, stream>>>(
        outF, outL, 0, 512, 512, WT_out, 1024, b_out, nullptr, nullptr,
        d_out, nullptr, nullptr, BIG, 4, 512, 1024,
        (const float*)conv2b, nullptr, nullptr, nullptr);
}

// Round 3
// 514.132 us; speedup vs baseline: 1.1001x; 1.1001x over previous
//
#include <hip/hip_runtime.h>
#include <hip/hip_bf16.h>

#define FFT_PI 3.14159265358979323846f
#define FOFF(i) ((i) + ((i) >> 3))   // padded LDS offset for row FFTs
#define CSW(r, c) ((c) ^ ((r) & 15)) // col-FFT LDS bank swizzle (bijective/row)

typedef __hip_bfloat16 bf16;
typedef short bf8_t __attribute__((ext_vector_type(8)));
typedef float f4_t __attribute__((ext_vector_type(4)));

__device__ inline float bf2f(unsigned short u) {
    union { unsigned int i; float f; } v; v.i = ((unsigned int)u) << 16; return v.f;
}
__device__ inline unsigned short f2bf(float f) {
    bf16 h = __float2bfloat16(f);
    union { bf16 h; unsigned short u; } v; v.h = h; return v.u;
}
__device__ inline float2 c_load(const ushort2* p) {
    ushort2 u = *p;
    return make_float2(bf2f(u.x), bf2f(u.y));
}
__device__ inline int brev6(int t) {
    return ((t & 1) << 5) | ((t & 2) << 3) | ((t & 4) << 1) |
           ((t & 8) >> 1) | ((t & 16) >> 3) | ((t & 32) >> 5);
}
__device__ inline float2 cadd(float2 a, float2 b){ return make_float2(a.x+b.x, a.y+b.y); }
__device__ inline float2 csub(float2 a, float2 b){ return make_float2(a.x-b.x, a.y-b.y); }
__device__ inline float2 cmul(float2 a, float2 b){
    return make_float2(a.x*b.x - a.y*b.y, a.x*b.y + a.y*b.x);
}
__device__ inline float2 cmuli(float2 a, float s){ return make_float2(-s*a.y, s*a.x); }

// async global->LDS, 16 B per lane; LDS dest = base + lane*16 (HW contract)
__device__ inline void async_load16(const void* gp, void* lp) {
    __builtin_amdgcn_global_load_lds(
        (const __attribute__((address_space(1))) void*)gp,
        (__attribute__((address_space(3))) void*)lp, 16, 0, 0);
}

// ---------------------------------------------------------------------------
// Merged transpose+convert for all 7 weights.
// ---------------------------------------------------------------------------
__global__ __launch_bounds__(256) void transpose_cvt_all(
    const float* __restrict__ s0, const float* __restrict__ s1,
    const float* __restrict__ s2, const float* __restrict__ s3,
    const float* __restrict__ s4, const float* __restrict__ s5,
    const float* __restrict__ s6, bf16* __restrict__ Wt)
{
    const int z = blockIdx.z;
    const int R = (z == 6) ? 1024 : 512;
    if (blockIdx.y * 32 >= R) return;
    const float* src = (z == 0) ? s0 : (z == 1) ? s1 : (z == 2) ? s2 :
                       (z == 3) ? s3 : (z == 4) ? s4 : (z == 5) ? s5 : s6;
    bf16* dst = Wt + (long)z * 262144;
    const int C = 512;

    __shared__ float tile[32][33];
    const int bx = blockIdx.x * 32;
    const int by = blockIdx.y * 32;
    const int tx = threadIdx.x, ty = threadIdx.y;
#pragma unroll
    for (int i = 0; i < 32; i += 8)
        tile[ty + i][tx] = src[(long)(by + ty + i) * C + bx + tx];
    __syncthreads();
#pragma unroll
    for (int i = 0; i < 32; i += 8)
        dst[(long)(bx + ty + i) * R + by + tx] = __float2bfloat16(tile[tx][ty + i]);
}

// ---------------------------------------------------------------------------
// MFMA bf16 GEMM v2: tile 128x128, BK=32, 4 waves. Unpadded LDS [128][32]
// shorts; global_load_lds width-16 staging for bf16 A (a_type 0) and all B.
// a_type: 0 = bf16 [m][k] (async), 1 = f32 [m][k] (manual convert).
// Two A buffers via ksplit. Multi-output via nper/sel. out_type as before.
// ---------------------------------------------------------------------------
__global__ __launch_bounds__(256) void mfma_gemm(
    const void* __restrict__ Av, const void* __restrict__ Av2,
    int a_type, int lda, int ksplit,
    const bf16* __restrict__ Bt, int ldb,
    const float* __restrict__ bias0, const float* __restrict__ bias1,
    const float* __restrict__ bias2,
    void* __restrict__ C0, void* __restrict__ C1, void* __restrict__ C2,
    int nper, int out_type, int ldc, int K,
    const float* __restrict__ e0, const float* __restrict__ e1,
    const float* __restrict__ e2, const float* __restrict__ e3)
{
    __shared__ short Asub[128 * 32];   // unpadded, 8 KB
    __shared__ short Bsub[128 * 32];

    const int tid = threadIdx.x;
    const int n0 = blockIdx.x * 128;
    const int m0 = blockIdx.y * 128;
    const int l  = tid & 63;
    const int wv = tid >> 6;
    const int wm = wv & 1, wn = wv >> 1;

    f4_t acc[4][4];
#pragma unroll
    for (int i = 0; i < 4; i++)
#pragma unroll
        for (int j = 0; j < 4; j++)
            acc[i][j] = (f4_t)0.f;

    const int crow = l >> 2;        // row within 16-row chunk
    const int cpc  = (l & 3) * 8;   // k-piece (shorts)

    for (int k0 = 0; k0 < K; k0 += 32) {
        const void* As = (k0 < ksplit) ? Av : Av2;
        const int kk = (k0 < ksplit) ? k0 : (k0 - ksplit);

        if (a_type == 0) {
#pragma unroll
            for (int c = 0; c < 2; c++) {
                const int chunk = wv * 2 + c;
                const int row = chunk * 16 + crow;
                async_load16((const bf16*)As + (long)(m0 + row) * lda + kk + cpc,
                             &Asub[chunk * 512]);
                async_load16(Bt + (long)(n0 + row) * ldb + k0 + cpc,
                             &Bsub[chunk * 512]);
            }
        } else {
            // manual f32 -> bf16 staging (conv2 GEMM only)
            const int srow = tid >> 2;
            const int sc8  = (tid & 3) * 8;
#pragma unroll
            for (int p = 0; p < 2; p++) {
                const int row = srow + p * 64;
                const float4* src = (const float4*)((const float*)As
                    + (long)(m0 + row) * lda + kk + sc8);
                float4 u0 = src[0], u1 = src[1];
                bf8_t av;
                av[0] = (short)f2bf(u0.x); av[1] = (short)f2bf(u0.y);
                av[2] = (short)f2bf(u0.z); av[3] = (short)f2bf(u0.w);
                av[4] = (short)f2bf(u1.x); av[5] = (short)f2bf(u1.y);
                av[6] = (short)f2bf(u1.z); av[7] = (short)f2bf(u1.w);
                *(bf8_t*)&Asub[row * 32 + sc8] = av;
            }
#pragma unroll
            for (int c = 0; c < 2; c++) {
                const int chunk = wv * 2 + c;
                const int row = chunk * 16 + crow;
                async_load16(Bt + (long)(n0 + row) * ldb + k0 + cpc,
                             &Bsub[chunk * 512]);
            }
        }
        __syncthreads();

        bf8_t a_frag[4], b_frag[4];
        const int ko = (l >> 4) * 8;
        const int lr = l & 15;
#pragma unroll
        for (int fm = 0; fm < 4; fm++)
            a_frag[fm] = *(bf8_t*)&Asub[(wm * 64 + fm * 16 + lr) * 32 + ko];
#pragma unroll
        for (int fn = 0; fn < 4; fn++)
            b_frag[fn] = *(bf8_t*)&Bsub[(wn * 64 + fn * 16 + lr) * 32 + ko];
#pragma unroll
        for (int fm = 0; fm < 4; fm++)
#pragma unroll
            for (int fn = 0; fn < 4; fn++)
                acc[fm][fn] = __builtin_amdgcn_mfma_f32_16x16x32_bf16(
                    b_frag[fn], a_frag[fm], acc[fm][fn], 0, 0, 0);
        __syncthreads();
    }

    const int sel = n0 / nper;
    const int nb  = sel * nper;
    const float* biasl = (sel == 0) ? bias0 : ((sel == 1) ? bias1 : bias2);
    void* Cl = (sel == 0) ? C0 : ((sel == 1) ? C1 : C2);

    const int em = m0 + wm * 64 + (l & 15);
    const int en = n0 + wn * 64 + ((l >> 4) << 2);
#pragma unroll
    for (int fm = 0; fm < 4; fm++) {
        const long m = em + fm * 16;
        float bnm = 0.f, bnr = 1.f, bng = 1.f, bnb = 0.f;
        if (out_type == 3) {
            const int c = (int)(m & 511);
            bnm = e0[c];
            bnr = 1.0f / sqrtf(e1[c] + 1e-5f);
            bng = e2[c];
            bnb = e3[c];
        }
#pragma unroll
        for (int fn = 0; fn < 4; fn++) {
            const int n = en + fn * 16;
            const int nl = n - nb;
            f4_t v = acc[fm][fn];
            if (biasl) {
#pragma unroll
                for (int r = 0; r < 4; r++) v[r] += biasl[nl + r];
            }
            if (out_type == 0) {
                float4 o; o.x = v[0]; o.y = v[1]; o.z = v[2]; o.w = v[3];
                *(float4*)((float*)Cl + m * ldc + nl) = o;
            } else if (out_type == 1) {
                union { unsigned short u[4]; ushort4 q; } o;
#pragma unroll
                for (int r = 0; r < 4; r++) o.u[r] = f2bf(v[r]);
                *(ushort4*)((bf16*)Cl + m * ldc + nl) = o.q;
            } else if (out_type == 2) {
                union { ushort2 u2[4]; uint4 q; } o;
#pragma unroll
                for (int r = 0; r < 4; r++) { o.u2[r].x = f2bf(v[r]); o.u2[r].y = 0; }
                *(uint4*)((ushort2*)Cl + m * ldc + nl) = o.q;
            } else if (out_type == 3) {
                union { unsigned short u[4]; ushort4 q; } o;
#pragma unroll
                for (int r = 0; r < 4; r++)
                    o.u[r] = f2bf(fmaxf((v[r] - bnm) * bnr * bng + bnb, 0.f));
                *(ushort4*)((bf16*)Cl + m * ldc + nl) = o.q;
            } else {
                union { unsigned short u[4]; ushort4 q; } rsd;
                rsd.q = *(const ushort4*)((const unsigned short*)e0 + m * ldc + nl);
                float4 o;
                o.x = v[0] + bf2f(rsd.u[0]);
                o.y = v[1] + bf2f(rsd.u[1]);
                o.z = v[2] + bf2f(rsd.u[2]);
                o.w = v[3] + bf2f(rsd.u[3]);
                *(float4*)((float*)Cl + m * ldc + nl) = o;
            }
        }
    }
}

// ---------------------------------------------------------------------------
// Radix-8 512-point Stockham FFT (two-buffer, row kernels).
// ---------------------------------------------------------------------------
__device__ inline void dft8(float2* x, float sgn)
{
    const float c45 = 0.70710678118654752f;
    float2 e0, e1, e2, e3, o0, o1, o2, o3;
    {
        float2 u0 = cadd(x[0], x[4]), u1 = csub(x[0], x[4]);
        float2 u2 = cadd(x[2], x[6]), u3 = cmuli(csub(x[2], x[6]), sgn);
        e0 = cadd(u0, u2); e1 = cadd(u1, u3); e2 = csub(u0, u2); e3 = csub(u1, u3);
    }
    {
        float2 u0 = cadd(x[1], x[5]), u1 = csub(x[1], x[5]);
        float2 u2 = cadd(x[3], x[7]), u3 = cmuli(csub(x[3], x[7]), sgn);
        o0 = cadd(u0, u2); o1 = cadd(u1, u3); o2 = csub(u0, u2); o3 = csub(u1, u3);
    }
    const float2 w1 = make_float2(c45, sgn * c45);
    const float2 w3 = make_float2(-c45, sgn * c45);
    o1 = cmul(o1, w1);
    o2 = cmuli(o2, sgn);
    o3 = cmul(o3, w3);
    x[0] = cadd(e0, o0); x[4] = csub(e0, o0);
    x[1] = cadd(e1, o1); x[5] = csub(e1, o1);
    x[2] = cadd(e2, o2); x[6] = csub(e2, o2);
    x[3] = cadd(e3, o3); x[7] = csub(e3, o3);
}

__device__ inline void fft512_r8(float2* bx0, float2* by0, int lane, float sign)
{
    float2* bx = bx0;
    float2* by = by0;
#pragma unroll
    for (int st = 0; st < 3; st++) {
        int n, m, sstr, p, q;
        if (st == 0)      { n = 512; m = 64; sstr = 1;  p = lane;      q = 0; }
        else if (st == 1) { n = 64;  m = 8;  sstr = 8;  p = lane >> 3; q = lane & 7; }
        else              { n = 8;   m = 1;  sstr = 64; p = 0;         q = lane; }
        float2 x[8];
#pragma unroll
        for (int r = 0; r < 8; r++) x[r] = bx[FOFF(q + sstr * (p + r * m))];
        dft8(x, sign);
        if (p) {
            float ang = sign * (2.0f * FFT_PI) * (float)p / (float)n;
            float sw, cw;
            __sincosf(ang, &sw, &cw);
            float2 w = make_float2(cw, sw), wk = w;
#pragma unroll
            for (int k = 1; k < 8; k++) { x[k] = cmul(x[k], wk); wk = cmul(wk, w); }
        }
#pragma unroll
        for (int k = 0; k < 8; k++) by[FOFF(q + sstr * (8 * p + k))] = x[k];
        __syncthreads();
        float2* t = bx; bx = by; by = t;
    }
}

// All forward row FFTs in one dispatch: buf 0..2 = Q/K/V c2c in-place;
// buf 3 = r2c conv2 -> Tb. 4 lines/block.
__global__ __launch_bounds__(256) void fft8_rows_all(
    ushort2* __restrict__ qkv, const bf16* __restrict__ conv2,
    ushort2* __restrict__ tb)
{
    __shared__ float2 B0[4][576], B1[4][576];
    const int buf = blockIdx.x >> 12;
    const int lb  = blockIdx.x & 4095;
    const int li = threadIdx.x >> 6, lane = threadIdx.x & 63;
    const long line = (long)lb * 4 + li;

    if (buf < 3) {
        ushort2* s = qkv + (long)buf * 8388608 + line * 512;
        uint4 r0 = *(const uint4*)(s + lane * 8);
        uint4 r1 = *(const uint4*)(s + lane * 8 + 4);
        float2* dst = &B0[li][9 * lane];
        const ushort2* pp = (const ushort2*)&r0;
#pragma unroll
        for (int j = 0; j < 4; j++) dst[j] = c_load(pp + j);
        pp = (const ushort2*)&r1;
#pragma unroll
        for (int j = 0; j < 4; j++) dst[4 + j] = c_load(pp + j);
        __syncthreads();
        fft512_r8(B0[li], B1[li], lane, -1.f);
        float2* src = &B1[li][9 * lane];
        union { ushort2 u[4]; uint4 q; } o0, o1;
#pragma unroll
        for (int j = 0; j < 4; j++) {
            float2 z = src[j]; o0.u[j].x = f2bf(z.x); o0.u[j].y = f2bf(z.y);
        }
#pragma unroll
        for (int j = 0; j < 4; j++) {
            float2 z = src[4 + j]; o1.u[j].x = f2bf(z.x); o1.u[j].y = f2bf(z.y);
        }
        *(uint4*)(s + lane * 8) = o0.q;
        *(uint4*)(s + lane * 8 + 4) = o1.q;
    } else {
        uint4 raw = *(const uint4*)((const unsigned short*)conv2 + line * 512 + lane * 8);
        const unsigned short* pp = (const unsigned short*)&raw;
        float2* d = &B0[li][9 * lane];
#pragma unroll
        for (int j = 0; j < 8; j++) d[j] = make_float2(bf2f(pp[j]), 0.f);
        __syncthreads();
        fft512_r8(B0[li], B1[li], lane, -1.f);
        ushort2* s = tb + line * 512;
        float2* src = &B1[li][9 * lane];
        union { ushort2 u[4]; uint4 q; } o0, o1;
#pragma unroll
        for (int j = 0; j < 4; j++) {
            float2 z = src[j]; o0.u[j].x = f2bf(z.x); o0.u[j].y = f2bf(z.y);
        }
#pragma unroll
        for (int j = 0; j < 4; j++) {
            float2 z = src[4 + j]; o1.u[j].x = f2bf(z.x); o1.u[j].y = f2bf(z.y);
        }
        *(uint4*)(s + lane * 8) = o0.q;
        *(uint4*)(s + lane * 8 + 4) = o1.q;
    }
}

// gated row inverse FFT: sigmoid(g2)*tep, ifft, scale 1/512, in place
__global__ __launch_bounds__(256) void fft8_rows_gated(
    const bf16* __restrict__ g2, ushort2* __restrict__ tep)
{
    __shared__ float2 B0[4][576], B1[4][576];
    const int li = threadIdx.x >> 6, lane = threadIdx.x & 63;
    const long line = (long)blockIdx.x * 4 + li;
    ushort2* s = tep + line * 512;
    {
        uint4 rg = *(const uint4*)((const unsigned short*)g2 + line * 512 + lane * 8);
        uint4 r0 = *(const uint4*)(s + lane * 8);
        uint4 r1 = *(const uint4*)(s + lane * 8 + 4);
        const unsigned short* gp = (const unsigned short*)&rg;
        float2* d = &B0[li][9 * lane];
        const ushort2* pp = (const ushort2*)&r0;
#pragma unroll
        for (int j = 0; j < 4; j++) {
            float sg = 1.0f / (1.0f + __expf(-bf2f(gp[j])));
            float2 z = c_load(pp + j);
            d[j] = make_float2(sg * z.x, sg * z.y);
        }
        pp = (const ushort2*)&r1;
#pragma unroll
        for (int j = 0; j < 4; j++) {
            float sg = 1.0f / (1.0f + __expf(-bf2f(gp[4 + j])));
            float2 z = c_load(pp + j);
            d[4 + j] = make_float2(sg * z.x, sg * z.y);
        }
    }
    __syncthreads();
    fft512_r8(B0[li], B1[li], lane, +1.f);
    {
        const float sc = 1.0f / 512.0f;
        float2* src = &B1[li][9 * lane];
        union { ushort2 u[4]; uint4 q; } o0, o1;
#pragma unroll
        for (int j = 0; j < 4; j++) {
            float2 z = src[j];
            o0.u[j].x = f2bf(z.x * sc); o0.u[j].y = f2bf(z.y * sc);
        }
#pragma unroll
        for (int j = 0; j < 4; j++) {
            float2 z = src[4 + j];
            o1.u[j].x = f2bf(z.x * sc); o1.u[j].y = f2bf(z.y * sc);
        }
        *(uint4*)(s + lane * 8) = o0.q;
        *(uint4*)(s + lane * 8 + 4) = o1.q;
    }
}

// ---------------------------------------------------------------------------
// Column FFT: 16 columns/block, single 64 KB LDS, in-place stages. Fused
// over 4 buffers (Q/K/V/T); buf==3 writes real parts to tepReal.
// 512 threads/block (2 butterfly roles/thread): LDS caps at 2 blocks/CU
// either way, so 512T doubles waves/CU 8 -> 16 for latency hiding.
// LDS col index XOR-swizzled with (row&15) (bank = f(col) only in the
// unswizzled [512][16] layout; swizzle spreads staging/output accesses
// across all banks - R1: conflicts 3.1M -> 1.0M).
// ---------------------------------------------------------------------------
__global__ __launch_bounds__(512) void fft8_cols16_c2c4(
    ushort2* __restrict__ data, bf16* __restrict__ tepReal, float sign)
{
    __shared__ float2 B[512][16];
    const int buf = blockIdx.x >> 10;
    const int rem = blockIdx.x & 1023;
    const int b   = rem >> 5;
    const int c0  = (rem & 31) * 16;
    ushort2* base = data + (long)buf * 8388608 + (long)b * 262144 + c0;
    const int t = threadIdx.x;
    const int lr = t >> 2;      // 0..127
    const int lq = t & 3;

#pragma unroll
    for (int it = 0; it < 4; it++) {
        const int row = it * 128 + lr;
        uint4 raw = *(const uint4*)(base + (long)row * 512 + lq * 4);
        const ushort2* pp = (const ushort2*)&raw;
#pragma unroll
        for (int j = 0; j < 4; j++) B[row][CSW(row, lq * 4 + j)] = c_load(pp + j);
    }
    __syncthreads();

    const int col = t & 15;
    const int rb  = t >> 4;     // 0..31
#pragma unroll
    for (int st = 0; st < 3; st++) {
        int n, m, s;
        if (st == 0)      { n = 512; m = 64; s = 1;  }
        else if (st == 1) { n = 64;  m = 8;  s = 8;  }
        else              { n = 8;   m = 1;  s = 64; }
        float2 x[2][8];
        int ps[2], qs[2];
#pragma unroll
        for (int i = 0; i < 2; i++) {
            const int role = rb + 32 * i;
            int p, q;
            if (st == 0)      { p = role;      q = 0; }
            else if (st == 1) { p = role >> 3; q = role & 7; }
            else              { p = 0;         q = role; }
            ps[i] = p; qs[i] = q;
#pragma unroll
            for (int r = 0; r < 8; r++) {
                const int rr = q + s * (p + r * m);
                x[i][r] = B[rr][CSW(rr, col)];
            }
        }
        __syncthreads();
#pragma unroll
        for (int i = 0; i < 2; i++) {
            dft8(x[i], sign);
            const int p = ps[i];
            if (p) {
                float ang = sign * (2.0f * FFT_PI) * (float)p / (float)n;
                float sw, cw;
                __sincosf(ang, &sw, &cw);
                float2 w = make_float2(cw, sw), wk = w;
#pragma unroll
                for (int k = 1; k < 8; k++) { x[i][k] = cmul(x[i][k], wk); wk = cmul(wk, w); }
            }
#pragma unroll
            for (int k = 0; k < 8; k++) {
                const int rw = qs[i] + s * (8 * p + k);
                B[rw][CSW(rw, col)] = x[i][k];
            }
        }
        __syncthreads();
    }

#pragma unroll
    for (int it = 0; it < 4; it++) {
        const int row = it * 128 + lr;
        union { ushort2 u[4]; uint4 q4; } o;
        union { unsigned short u[4]; ushort4 q4; } orl;
#pragma unroll
        for (int j = 0; j < 4; j++) {
            float2 z = B[row][CSW(row, lq * 4 + j)];
            o.u[j].x = f2bf(z.x); o.u[j].y = f2bf(z.y);
            orl.u[j] = o.u[j].x;
        }
        *(uint4*)(base + (long)row * 512 + lq * 4) = o.q4;
        if (buf == 3)
            *(ushort4*)(tepReal + (long)b * 262144 + (long)row * 512 + c0 + lq * 4) = orl.q4;
    }
}

// Column inverse FFT + abs -> bf16 real (scale 1/512), 16 columns/block,
// 512 threads (same restructure as c2c4).
__global__ __launch_bounds__(512) void fft8_cols16_abs(
    const ushort2* __restrict__ src, bf16* __restrict__ dst)
{
    __shared__ float2 B[512][16];
    const int b  = blockIdx.x >> 5;
    const int c0 = (blockIdx.x & 31) * 16;
    const ushort2* base = src + (long)b * 262144 + c0;
    const int t = threadIdx.x;
    const int lr = t >> 2;
    const int lq = t & 3;

#pragma unroll
    for (int it = 0; it < 4; it++) {
        const int row = it * 128 + lr;
        uint4 raw = *(const uint4*)(base + (long)row * 512 + lq * 4);
        const ushort2* pp = (const ushort2*)&raw;
#pragma unroll
        for (int j = 0; j < 4; j++) B[row][CSW(row, lq * 4 + j)] = c_load(pp + j);
    }
    __syncthreads();

    const int col = t & 15;
    const int rb  = t >> 4;
#pragma unroll
    for (int st = 0; st < 3; st++) {
        int n, m, s;
        if (st == 0)      { n = 512; m = 64; s = 1;  }
        else if (st == 1) { n = 64;  m = 8;  s = 8;  }
        else              { n = 8;   m = 1;  s = 64; }
        float2 x[2][8];
        int ps[2], qs[2];
#pragma unroll
        for (int i = 0; i < 2; i++) {
            const int role = rb + 32 * i;
            int p, q;
            if (st == 0)      { p = role;      q = 0; }
            else if (st == 1) { p = role >> 3; q = role & 7; }
            else              { p = 0;         q = role; }
            ps[i] = p; qs[i] = q;
#pragma unroll
            for (int r = 0; r < 8; r++) {
                const int rr = q + s * (p + r * m);
                x[i][r] = B[rr][CSW(rr, col)];
            }
        }
        __syncthreads();
#pragma unroll
        for (int i = 0; i < 2; i++) {
            dft8(x[i], +1.f);
            const int p = ps[i];
            if (p) {
                float ang = (2.0f * FFT_PI) * (float)p / (float)n;
                float sw, cw;
                __sincosf(ang, &sw, &cw);
                float2 w = make_float2(cw, sw), wk = w;
#pragma unroll
                for (int k = 1; k < 8; k++) { x[i][k] = cmul(x[i][k], wk); wk = cmul(wk, w); }
            }
#pragma unroll
            for (int k = 0; k < 8; k++) {
                const int rw = qs[i] + s * (8 * p + k);
                B[rw][CSW(rw, col)] = x[i][k];
            }
        }
        __syncthreads();
    }

    const float sc = 1.0f / 512.0f;
#pragma unroll
    for (int it = 0; it < 4; it++) {
        const int row = it * 128 + lr;
        union { unsigned short u[4]; ushort4 q4; } o;
#pragma unroll
        for (int j = 0; j < 4; j++) {
            float2 z = B[row][CSW(row, lq * 4 + j)];
            o.u[j] = f2bf(sqrtf(z.x * z.x + z.y * z.y) * sc);
        }
        *(ushort4*)(dst + (long)b * 262144 + (long)row * 512 + c0 + lq * 4) = o.q4;
    }
}

// ---------------------------------------------------------------------------
// attn v4: 4 (b,c) per block; raw bf16 LDS staging (no pre-normalize pass —
// norms folded into the score loop), LDS ~19.7 KB -> 8 blocks/CU.
// Row pad 68 complex: 272 B stride keeps uint4 alignment and spreads the 8
// head-rows over banks 4h..4h+3 (conflict-free broadcast reads).
// ---------------------------------------------------------------------------
__global__ __launch_bounds__(256) void attn_kernel(
    const ushort2* __restrict__ qf, const ushort2* __restrict__ kf,
    const ushort2* __restrict__ vf, const float* __restrict__ temp,
    bf16* __restrict__ out_f)
{
    __shared__ ushort2 QS[4][8][68];   // raw bf16 q rows
    __shared__ ushort2 KS[4][8][68];   // raw bf16 k rows
    __shared__ float2 ATT[4][8][9];

    const int li = threadIdx.x >> 6, lane = threadIdx.x & 63;
    const int bc = blockIdx.x * 4 + li;
    const long base = (long)bc * 512;

    // stage raw bf16 q,k rows: 2x uint4 (4 complex) per lane per buffer
    {
        const int h1 = lane >> 4, w1 = (lane & 15) * 4;
        uint4 q0 = *(const uint4*)(qf + base + lane * 4);
        uint4 q1 = *(const uint4*)(qf + base + 256 + lane * 4);
        uint4 k0 = *(const uint4*)(kf + base + lane * 4);
        uint4 k1 = *(const uint4*)(kf + base + 256 + lane * 4);
        *(uint4*)&QS[li][h1][w1]     = q0;
        *(uint4*)&QS[li][h1 + 4][w1] = q1;
        *(uint4*)&KS[li][h1][w1]     = k0;
        *(uint4*)&KS[li][h1 + 4][w1] = k1;
    }
    float2 v[8];
#pragma unroll
    for (int h = 0; h < 8; h++)
        v[h] = c_load(vf + base + h * 64 + lane);
    __syncthreads();

    // scores + norms + softmax, fully parallel: lane = (h = lane>>3, g = lane&7)
    // score[h][g] = (q_h . k_g) * temp[h] / (|q_h| |k_g|)  ==  normalized dot
    {
        const int h = lane >> 3, g = lane & 7;
        float ar = 0.f, ai = 0.f, nq = 0.f, nk = 0.f;
#pragma unroll
        for (int w = 0; w < 64; w += 4) {
            uint4 qa = *(const uint4*)&QS[li][h][w];
            uint4 kb = *(const uint4*)&KS[li][g][w];
            const unsigned short* qs = (const unsigned short*)&qa;
            const unsigned short* ks = (const unsigned short*)&kb;
#pragma unroll
            for (int j = 0; j < 4; j++) {
                float qx = bf2f(qs[2 * j]), qy = bf2f(qs[2 * j + 1]);
                float kx = bf2f(ks[2 * j]), ky = bf2f(ks[2 * j + 1]);
                ar += qx * kx - qy * ky;
                ai += qx * ky + qy * kx;
                nq += qx * qx + qy * qy;
                nk += kx * kx + ky * ky;
            }
        }
        const float iq = 1.0f / fmaxf(sqrtf(nq), 1e-12f);
        const float ik = 1.0f / fmaxf(sqrtf(nk), 1e-12f);
        const float s = temp[h] * iq * ik;
        ar *= s; ai *= s;
        // group-of-8 max (offsets 1,2,4 stay within the h-group)
        float mr = ar, mi = ai;
#pragma unroll
        for (int o = 1; o < 8; o <<= 1) {
            mr = fmaxf(mr, __shfl_xor(mr, o, 64));
            mi = fmaxf(mi, __shfl_xor(mi, o, 64));
        }
        float er = __expf(ar - mr), ei = __expf(ai - mi);
        float sr = er, si = ei;
#pragma unroll
        for (int o = 1; o < 8; o <<= 1) {
            sr += __shfl_xor(sr, o, 64);
            si += __shfl_xor(si, o, 64);
        }
        ATT[li][h][g] = make_float2(er / sr, ei / si);
    }
    __syncthreads();

    float2 o[8];
#pragma unroll
    for (int h = 0; h < 8; h++) {
        float orr = 0.f, oi = 0.f;
#pragma unroll
        for (int g = 0; g < 8; g++) {
            float2 a = ATT[li][h][g], b = v[g];
            orr += a.x * b.x - a.y * b.y;
            oi  += a.x * b.y + a.y * b.x;
        }
        o[h] = make_float2(orr, oi);
    }

#pragma unroll
    for (int m = 32; m >= 1; m >>= 1) {
        float ang = (FFT_PI / (float)m) * (float)(lane & (m - 1));
        float sw, cw;
        __sincosf(ang, &sw, &cw);
        const bool low = (lane & m) == 0;
#pragma unroll
        for (int h = 0; h < 8; h++) {
            float px = __shfl_xor(o[h].x, m, 64);
            float py = __shfl_xor(o[h].y, m, 64);
            float nx, ny;
            if (low) {
                nx = o[h].x + px;
                ny = o[h].y + py;
            } else {
                float dx = px - o[h].x;
                float dy = py - o[h].y;
                nx = dx * cw - dy * sw;
                ny = dx * sw + dy * cw;
            }
            o[h].x = nx; o[h].y = ny;
        }
    }
    const int wr = brev6(lane);

    const float r2 = 0.70710678118654752f;
    const float W8x[8] = {1.f,  r2, 0.f, -r2, -1.f, -r2,  0.f,  r2};
    const float W8y[8] = {0.f,  r2, 1.f,  r2,  0.f, -r2, -1.f, -r2};
    unsigned short* stg = (unsigned short*)&QS[li][0][0];
#pragma unroll
    for (int kh = 0; kh < 8; kh++) {
        float sr = 0.f, si = 0.f;
#pragma unroll
        for (int n = 0; n < 8; n++) {
            const int idx = (n * kh) & 7;
            float wx = W8x[idx], wy = W8y[idx];
            sr += o[n].x * wx - o[n].y * wy;
            si += o[n].x * wy + o[n].y * wx;
        }
        stg[kh * 64 + wr] = f2bf(sqrtf(sr * sr + si * si) * (1.0f / 512.0f));
    }
    __syncthreads();
    uint4 ov = *(uint4*)(stg + lane * 8);
    *(uint4*)((unsigned short*)out_f + base + lane * 8) = ov;
}

// ---------------------------------------------------------------------------
extern "C" void kernel_launch(void* const* d_in, const int* in_sizes, int n_in,
                              void* d_out, int out_size, void* d_ws, size_t ws_size,
                              hipStream_t stream)
{
    const float* x     = (const float*)d_in[0];
    const float* W_in  = (const float*)d_in[1];
    const float* b_in  = (const float*)d_in[2];
    const float* W_q   = (const float*)d_in[3];
    const float* b_q   = (const float*)d_in[4];
    const float* W_k   = (const float*)d_in[5];
    const float* b_k   = (const float*)d_in[6];
    const float* W_v   = (const float*)d_in[7];
    const float* b_v   = (const float*)d_in[8];
    const float* temp  = (const float*)d_in[9];
    const float* W1a   = (const float*)d_in[10];
    const float* b1a   = (const float*)d_in[11];
    const float* gam   = (const float*)d_in[12];
    const float* bet   = (const float*)d_in[13];
    const float* mea   = (const float*)d_in[14];
    const float* var   = (const float*)d_in[15];
    const float* W1b   = (const float*)d_in[16];
    const float* b1b   = (const float*)d_in[17];
    const float* W_out = (const float*)d_in[18];
    const float* b_out = (const float*)d_in[19];

    char* wsb = (char*)d_ws;
    const long MB = 1024 * 1024;
    bf16*    conv2b  = (bf16*)wsb;
    bf16*    tepReal = (bf16*)(wsb + 16 * MB);
    ushort2* Qb    = (ushort2*)(wsb + 32 * MB);
    ushort2* Kb    = (ushort2*)(wsb + 64 * MB);
    ushort2* Vb    = (ushort2*)(wsb + 96 * MB);
    ushort2* Tb    = (ushort2*)(wsb + 128 * MB);
    bf16*    Wt    = (bf16*)(wsb + 160 * MB);
    bf16* WT_in  = Wt;
    bf16* WT_q   = Wt + 262144;
    bf16* WT_1a  = Wt + 4 * 262144;
    bf16* WT_1b  = Wt + 5 * 262144;
    bf16* WT_out = Wt + 6 * 262144;
    bf16* outF = (bf16*)Qb;
    bf16* g1b  = (bf16*)Kb;
    bf16* outL = (bf16*)Kb;
    bf16* g2b  = (bf16*)Vb;

    const dim3 ggrid(4, 128), gblk(256);
    const int BIG = 1 << 30;
    const int RB = 4096;

    transpose_cvt_all<<<dim3(16, 32, 7), dim3(32, 8), 0, stream>>>(
        W_in, W_q, W_k, W_v, W1a, W1b, W_out, Wt);

    // 1. conv2 = x @ W_in + b_in -> bf16  (f32 A, manual staging)
    mfma_gemm<<<ggrid, gblk, 0, stream>>>(
        x, x, 1, 512, BIG, WT_in, 512, b_in, nullptr, nullptr,
        conv2b, nullptr, nullptr, BIG, 1, 512, 512,
        nullptr, nullptr, nullptr, nullptr);

    // 2. fused q/k/v projections (async staging)
    mfma_gemm<<<dim3(12, 128), gblk, 0, stream>>>(
        conv2b, conv2b, 0, 512, BIG, WT_q, 512, b_q, b_k, b_v,
        Qb, Kb, Vb, 512, 2, 512, 512,
        nullptr, nullptr, nullptr, nullptr);

    // 3. all row FFTs (Q/K/V c2c + tep r2c) in one dispatch
    fft8_rows_all<<<4 * RB, 256, 0, stream>>>(Qb, conv2b, Tb);

    // 4. col FFTs: Q,K,V,T fused, 16 cols/block, 512 threads
    fft8_cols16_c2c4<<<4096, 512, 0, stream>>>(Qb, tepReal, -1.f);

    // 5. attention -> out_f bf16 over Qb
    attn_kernel<<<RB, 256, 0, stream>>>(Qb, Kb, Vb, temp, outF);

    // 6. g1 = BN_ReLU(tepReal @ W1a + b1a) -> bf16
    mfma_gemm<<<ggrid, gblk, 0, stream>>>(
        tepReal, tepReal, 0, 512, BIG, WT_1a, 512, b1a, nullptr, nullptr,
        g1b, nullptr, nullptr, BIG, 3, 512, 512,
        mea, var, gam, bet);

    // 7. g2 = g1 @ W1b + b1b -> bf16
    mfma_gemm<<<ggrid, gblk, 0, stream>>>(
        g1b, g1b, 0, 512, BIG, WT_1b, 512, b1b, nullptr, nullptr,
        g2b, nullptr, nullptr, BIG, 1, 512, 512,
        nullptr, nullptr, nullptr, nullptr);

    // 8. gated ifft2 + abs -> out_l bf16 (over Kb)
    fft8_rows_gated<<<RB, 256, 0, stream>>>(g2b, Tb);
    fft8_cols16_abs<<<1024, 512, 0, stream>>>(Tb, outL);

    // 9. d_out = [out_f | out_l] @ W_out + b_out + conv2 (K=1024, fused residual)
    mfma_gemm<<<ggrid, gblk, 0, stream>>>(
        outF, outL, 0, 512, 512, WT_out, 1024, b_out, nullptr, nullptr,
        d_out, nullptr, nullptr, BIG, 4, 512, 1024,
        (const float*)conv2b, nullptr, nullptr, nullptr);
}

// Round 5
// 513.430 us; speedup vs baseline: 1.1016x; 1.0014x over previous
//
#include <hip/hip_runtime.h>
#include <hip/hip_bf16.h>

#define FFT_PI 3.14159265358979323846f
#define FOFF(i) ((i) + ((i) >> 3))   // padded LDS offset for row FFTs
#define CSW(r, c) ((c) ^ ((r) & 15)) // col-FFT LDS bank swizzle (bijective/row)

typedef __hip_bfloat16 bf16;
typedef short bf8_t __attribute__((ext_vector_type(8)));
typedef float f4_t __attribute__((ext_vector_type(4)));

__device__ inline float bf2f(unsigned short u) {
    union { unsigned int i; float f; } v; v.i = ((unsigned int)u) << 16; return v.f;
}
__device__ inline unsigned short f2bf(float f) {
    bf16 h = __float2bfloat16(f);
    union { bf16 h; unsigned short u; } v; v.h = h; return v.u;
}
__device__ inline float2 c_load(const ushort2* p) {
    ushort2 u = *p;
    return make_float2(bf2f(u.x), bf2f(u.y));
}
__device__ inline int brev6(int t) {
    return ((t & 1) << 5) | ((t & 2) << 3) | ((t & 4) << 1) |
           ((t & 8) >> 1) | ((t & 16) >> 3) | ((t & 32) >> 5);
}
__device__ inline float2 cadd(float2 a, float2 b){ return make_float2(a.x+b.x, a.y+b.y); }
__device__ inline float2 csub(float2 a, float2 b){ return make_float2(a.x-b.x, a.y-b.y); }
__device__ inline float2 cmul(float2 a, float2 b){
    return make_float2(a.x*b.x - a.y*b.y, a.x*b.y + a.y*b.x);
}
__device__ inline float2 cmuli(float2 a, float s){ return make_float2(-s*a.y, s*a.x); }

// twiddle fetch from LDS table: TWL[j] = exp(+2*pi*i*j/512)
__device__ inline float2 twd(const float2* TWL, int j, float sign) {
    float2 t = TWL[j];
    return make_float2(t.x, sign * t.y);
}

// async global->LDS, 16 B per lane; LDS dest = base + lane*16 (HW contract)
__device__ inline void async_load16(const void* gp, void* lp) {
    __builtin_amdgcn_global_load_lds(
        (const __attribute__((address_space(1))) void*)gp,
        (__attribute__((address_space(3))) void*)lp, 16, 0, 0);
}

// ---------------------------------------------------------------------------
// Merged transpose+convert for all 7 weights.
// ---------------------------------------------------------------------------
__global__ __launch_bounds__(256) void transpose_cvt_all(
    const float* __restrict__ s0, const float* __restrict__ s1,
    const float* __restrict__ s2, const float* __restrict__ s3,
    const float* __restrict__ s4, const float* __restrict__ s5,
    const float* __restrict__ s6, bf16* __restrict__ Wt)
{
    const int z = blockIdx.z;
    const int R = (z == 6) ? 1024 : 512;
    if (blockIdx.y * 32 >= R) return;
    const float* src = (z == 0) ? s0 : (z == 1) ? s1 : (z == 2) ? s2 :
                       (z == 3) ? s3 : (z == 4) ? s4 : (z == 5) ? s5 : s6;
    bf16* dst = Wt + (long)z * 262144;
    const int C = 512;

    __shared__ float tile[32][33];
    const int bx = blockIdx.x * 32;
    const int by = blockIdx.y * 32;
    const int tx = threadIdx.x, ty = threadIdx.y;
#pragma unroll
    for (int i = 0; i < 32; i += 8)
        tile[ty + i][tx] = src[(long)(by + ty + i) * C + bx + tx];
    __syncthreads();
#pragma unroll
    for (int i = 0; i < 32; i += 8)
        dst[(long)(bx + ty + i) * R + by + tx] = __float2bfloat16(tile[tx][ty + i]);
}

// ---------------------------------------------------------------------------
// MFMA bf16 GEMM v2: tile 128x128, BK=32, 4 waves. Unpadded LDS [128][32]
// shorts; global_load_lds width-16 staging for bf16 A (a_type 0) and all B.
// a_type: 0 = bf16 [m][k] (async), 1 = f32 [m][k] (manual convert).
// Two A buffers via ksplit. Multi-output via nper/sel. out_type as before.
// ---------------------------------------------------------------------------
__global__ __launch_bounds__(256) void mfma_gemm(
    const void* __restrict__ Av, const void* __restrict__ Av2,
    int a_type, int lda, int ksplit,
    const bf16* __restrict__ Bt, int ldb,
    const float* __restrict__ bias0, const float* __restrict__ bias1,
    const float* __restrict__ bias2,
    void* __restrict__ C0, void* __restrict__ C1, void* __restrict__ C2,
    int nper, int out_type, int ldc, int K,
    const float* __restrict__ e0, const float* __restrict__ e1,
    const float* __restrict__ e2, const float* __restrict__ e3)
{
    __shared__ short Asub[128 * 32];   // unpadded, 8 KB
    __shared__ short Bsub[128 * 32];

    const int tid = threadIdx.x;
    const int n0 = blockIdx.x * 128;
    const int m0 = blockIdx.y * 128;
    const int l  = tid & 63;
    const int wv = tid >> 6;
    const int wm = wv & 1, wn = wv >> 1;

    f4_t acc[4][4];
#pragma unroll
    for (int i = 0; i < 4; i++)
#pragma unroll
        for (int j = 0; j < 4; j++)
            acc[i][j] = (f4_t)0.f;

    const int crow = l >> 2;        // row within 16-row chunk
    const int cpc  = (l & 3) * 8;   // k-piece (shorts)

    for (int k0 = 0; k0 < K; k0 += 32) {
        const void* As = (k0 < ksplit) ? Av : Av2;
        const int kk = (k0 < ksplit) ? k0 : (k0 - ksplit);

        if (a_type == 0) {
#pragma unroll
            for (int c = 0; c < 2; c++) {
                const int chunk = wv * 2 + c;
                const int row = chunk * 16 + crow;
                async_load16((const bf16*)As + (long)(m0 + row) * lda + kk + cpc,
                             &Asub[chunk * 512]);
                async_load16(Bt + (long)(n0 + row) * ldb + k0 + cpc,
                             &Bsub[chunk * 512]);
            }
        } else {
            // manual f32 -> bf16 staging (conv2 GEMM only)
            const int srow = tid >> 2;
            const int sc8  = (tid & 3) * 8;
#pragma unroll
            for (int p = 0; p < 2; p++) {
                const int row = srow + p * 64;
                const float4* src = (const float4*)((const float*)As
                    + (long)(m0 + row) * lda + kk + sc8);
                float4 u0 = src[0], u1 = src[1];
                bf8_t av;
                av[0] = (short)f2bf(u0.x); av[1] = (short)f2bf(u0.y);
                av[2] = (short)f2bf(u0.z); av[3] = (short)f2bf(u0.w);
                av[4] = (short)f2bf(u1.x); av[5] = (short)f2bf(u1.y);
                av[6] = (short)f2bf(u1.z); av[7] = (short)f2bf(u1.w);
                *(bf8_t*)&Asub[row * 32 + sc8] = av;
            }
#pragma unroll
            for (int c = 0; c < 2; c++) {
                const int chunk = wv * 2 + c;
                const int row = chunk * 16 + crow;
                async_load16(Bt + (long)(n0 + row) * ldb + k0 + cpc,
                             &Bsub[chunk * 512]);
            }
        }
        __syncthreads();

        bf8_t a_frag[4], b_frag[4];
        const int ko = (l >> 4) * 8;
        const int lr = l & 15;
#pragma unroll
        for (int fm = 0; fm < 4; fm++)
            a_frag[fm] = *(bf8_t*)&Asub[(wm * 64 + fm * 16 + lr) * 32 + ko];
#pragma unroll
        for (int fn = 0; fn < 4; fn++)
            b_frag[fn] = *(bf8_t*)&Bsub[(wn * 64 + fn * 16 + lr) * 32 + ko];
#pragma unroll
        for (int fm = 0; fm < 4; fm++)
#pragma unroll
            for (int fn = 0; fn < 4; fn++)
                acc[fm][fn] = __builtin_amdgcn_mfma_f32_16x16x32_bf16(
                    b_frag[fn], a_frag[fm], acc[fm][fn], 0, 0, 0);
        __syncthreads();
    }

    const int sel = n0 / nper;
    const int nb  = sel * nper;
    const float* biasl = (sel == 0) ? bias0 : ((sel == 1) ? bias1 : bias2);
    void* Cl = (sel == 0) ? C0 : ((sel == 1) ? C1 : C2);

    const int em = m0 + wm * 64 + (l & 15);
    const int en = n0 + wn * 64 + ((l >> 4) << 2);
#pragma unroll
    for (int fm = 0; fm < 4; fm++) {
        const long m = em + fm * 16;
        float bnm = 0.f, bnr = 1.f, bng = 1.f, bnb = 0.f;
        if (out_type == 3) {
            const int c = (int)(m & 511);
            bnm = e0[c];
            bnr = 1.0f / sqrtf(e1[c] + 1e-5f);
            bng = e2[c];
            bnb = e3[c];
        }
#pragma unroll
        for (int fn = 0; fn < 4; fn++) {
            const int n = en + fn * 16;
            const int nl = n - nb;
            f4_t v = acc[fm][fn];
            if (biasl) {
#pragma unroll
                for (int r = 0; r < 4; r++) v[r] += biasl[nl + r];
            }
            if (out_type == 0) {
                float4 o; o.x = v[0]; o.y = v[1]; o.z = v[2]; o.w = v[3];
                *(float4*)((float*)Cl + m * ldc + nl) = o;
            } else if (out_type == 1) {
                union { unsigned short u[4]; ushort4 q; } o;
#pragma unroll
                for (int r = 0; r < 4; r++) o.u[r] = f2bf(v[r]);
                *(ushort4*)((bf16*)Cl + m * ldc + nl) = o.q;
            } else if (out_type == 2) {
                union { ushort2 u2[4]; uint4 q; } o;
#pragma unroll
                for (int r = 0; r < 4; r++) { o.u2[r].x = f2bf(v[r]); o.u2[r].y = 0; }
                *(uint4*)((ushort2*)Cl + m * ldc + nl) = o.q;
            } else if (out_type == 3) {
                union { unsigned short u[4]; ushort4 q; } o;
#pragma unroll
                for (int r = 0; r < 4; r++)
                    o.u[r] = f2bf(fmaxf((v[r] - bnm) * bnr * bng + bnb, 0.f));
                *(ushort4*)((bf16*)Cl + m * ldc + nl) = o.q;
            } else {
                union { unsigned short u[4]; ushort4 q; } rsd;
                rsd.q = *(const ushort4*)((const unsigned short*)e0 + m * ldc + nl);
                float4 o;
                o.x = v[0] + bf2f(rsd.u[0]);
                o.y = v[1] + bf2f(rsd.u[1]);
                o.z = v[2] + bf2f(rsd.u[2]);
                o.w = v[3] + bf2f(rsd.u[3]);
                *(float4*)((float*)Cl + m * ldc + nl) = o;
            }
        }
    }
}

// ---------------------------------------------------------------------------
// Radix-8 512-point Stockham FFT (two-buffer, row kernels). Twiddles from a
// per-block LDS table TWL[j] = exp(+2*pi*i*j/512): 7 independent ds_reads +
// cmuls replace sincos + 7-deep serial cmul chain (indices p*k*(512/n) <= 441).
// ---------------------------------------------------------------------------
__device__ inline void dft8(float2* x, float sgn)
{
    const float c45 = 0.70710678118654752f;
    float2 e0, e1, e2, e3, o0, o1, o2, o3;
    {
        float2 u0 = cadd(x[0], x[4]), u1 = csub(x[0], x[4]);
        float2 u2 = cadd(x[2], x[6]), u3 = cmuli(csub(x[2], x[6]), sgn);
        e0 = cadd(u0, u2); e1 = cadd(u1, u3); e2 = csub(u0, u2); e3 = csub(u1, u3);
    }
    {
        float2 u0 = cadd(x[1], x[5]), u1 = csub(x[1], x[5]);
        float2 u2 = cadd(x[3], x[7]), u3 = cmuli(csub(x[3], x[7]), sgn);
        o0 = cadd(u0, u2); o1 = cadd(u1, u3); o2 = csub(u0, u2); o3 = csub(u1, u3);
    }
    const float2 w1 = make_float2(c45, sgn * c45);
    const float2 w3 = make_float2(-c45, sgn * c45);
    o1 = cmul(o1, w1);
    o2 = cmuli(o2, sgn);
    o3 = cmul(o3, w3);
    x[0] = cadd(e0, o0); x[4] = csub(e0, o0);
    x[1] = cadd(e1, o1); x[5] = csub(e1, o1);
    x[2] = cadd(e2, o2); x[6] = csub(e2, o2);
    x[3] = cadd(e3, o3); x[7] = csub(e3, o3);
}

__device__ inline void fft512_r8(float2* bx0, float2* by0, int lane, float sign,
                                 const float2* TWL)
{
    float2* bx = bx0;
    float2* by = by0;
#pragma unroll
    for (int st = 0; st < 3; st++) {
        int n, m, sstr, p, q;
        if (st == 0)      { n = 512; m = 64; sstr = 1;  p = lane;      q = 0; }
        else if (st == 1) { n = 64;  m = 8;  sstr = 8;  p = lane >> 3; q = lane & 7; }
        else              { n = 8;   m = 1;  sstr = 64; p = 0;         q = lane; }
        float2 x[8];
#pragma unroll
        for (int r = 0; r < 8; r++) x[r] = bx[FOFF(q + sstr * (p + r * m))];
        dft8(x, sign);
        if (p) {
            const int step = (st == 0) ? 1 : 8;   // 512/n
#pragma unroll
            for (int k = 1; k < 8; k++)
                x[k] = cmul(x[k], twd(TWL, p * k * step, sign));
        }
#pragma unroll
        for (int k = 0; k < 8; k++) by[FOFF(q + sstr * (8 * p + k))] = x[k];
        __syncthreads();
        float2* t = bx; bx = by; by = t;
    }
}

// fill LDS twiddle table; caller must have a __syncthreads() before first use
__device__ inline void twl_fill(float2* TWL, int t, int nthreads)
{
    for (int j = t; j < 512; j += nthreads) {
        float sw, cw;
        __sincosf((2.0f * FFT_PI) * (float)j / 512.0f, &sw, &cw);
        TWL[j] = make_float2(cw, sw);
    }
}

// All forward row FFTs in one dispatch: buf 0..2 = Q/K/V c2c in-place;
// buf 3 = r2c conv2 -> Tb. 4 lines/block.
__global__ __launch_bounds__(256) void fft8_rows_all(
    ushort2* __restrict__ qkv, const bf16* __restrict__ conv2,
    ushort2* __restrict__ tb)
{
    __shared__ float2 B0[4][576], B1[4][576];
    __shared__ float2 TWL[512];
    const int buf = blockIdx.x >> 12;
    const int lb  = blockIdx.x & 4095;
    const int li = threadIdx.x >> 6, lane = threadIdx.x & 63;
    const long line = (long)lb * 4 + li;
    twl_fill(TWL, threadIdx.x, 256);

    if (buf < 3) {
        ushort2* s = qkv + (long)buf * 8388608 + line * 512;
        uint4 r0 = *(const uint4*)(s + lane * 8);
        uint4 r1 = *(const uint4*)(s + lane * 8 + 4);
        float2* dst = &B0[li][9 * lane];
        const ushort2* pp = (const ushort2*)&r0;
#pragma unroll
        for (int j = 0; j < 4; j++) dst[j] = c_load(pp + j);
        pp = (const ushort2*)&r1;
#pragma unroll
        for (int j = 0; j < 4; j++) dst[4 + j] = c_load(pp + j);
        __syncthreads();
        fft512_r8(B0[li], B1[li], lane, -1.f, TWL);
        float2* src = &B1[li][9 * lane];
        union { ushort2 u[4]; uint4 q; } o0, o1;
#pragma unroll
        for (int j = 0; j < 4; j++) {
            float2 z = src[j]; o0.u[j].x = f2bf(z.x); o0.u[j].y = f2bf(z.y);
        }
#pragma unroll
        for (int j = 0; j < 4; j++) {
            float2 z = src[4 + j]; o1.u[j].x = f2bf(z.x); o1.u[j].y = f2bf(z.y);
        }
        *(uint4*)(s + lane * 8) = o0.q;
        *(uint4*)(s + lane * 8 + 4) = o1.q;
    } else {
        uint4 raw = *(const uint4*)((const unsigned short*)conv2 + line * 512 + lane * 8);
        const unsigned short* pp = (const unsigned short*)&raw;
        float2* d = &B0[li][9 * lane];
#pragma unroll
        for (int j = 0; j < 8; j++) d[j] = make_float2(bf2f(pp[j]), 0.f);
        __syncthreads();
        fft512_r8(B0[li], B1[li], lane, -1.f, TWL);
        ushort2* s = tb + line * 512;
        float2* src = &B1[li][9 * lane];
        union { ushort2 u[4]; uint4 q; } o0, o1;
#pragma unroll
        for (int j = 0; j < 4; j++) {
            float2 z = src[j]; o0.u[j].x = f2bf(z.x); o0.u[j].y = f2bf(z.y);
        }
#pragma unroll
        for (int j = 0; j < 4; j++) {
            float2 z = src[4 + j]; o1.u[j].x = f2bf(z.x); o1.u[j].y = f2bf(z.y);
        }
        *(uint4*)(s + lane * 8) = o0.q;
        *(uint4*)(s + lane * 8 + 4) = o1.q;
    }
}

// gated row inverse FFT: sigmoid(g2)*tep, ifft, scale 1/512, in place
__global__ __launch_bounds__(256) void fft8_rows_gated(
    const bf16* __restrict__ g2, ushort2* __restrict__ tep)
{
    __shared__ float2 B0[4][576], B1[4][576];
    __shared__ float2 TWL[512];
    const int li = threadIdx.x >> 6, lane = threadIdx.x & 63;
    const long line = (long)blockIdx.x * 4 + li;
    ushort2* s = tep + line * 512;
    twl_fill(TWL, threadIdx.x, 256);
    {
        uint4 rg = *(const uint4*)((const unsigned short*)g2 + line * 512 + lane * 8);
        uint4 r0 = *(const uint4*)(s + lane * 8);
        uint4 r1 = *(const uint4*)(s + lane * 8 + 4);
        const unsigned short* gp = (const unsigned short*)&rg;
        float2* d = &B0[li][9 * lane];
        const ushort2* pp = (const ushort2*)&r0;
#pragma unroll
        for (int j = 0; j < 4; j++) {
            float sg = 1.0f / (1.0f + __expf(-bf2f(gp[j])));
            float2 z = c_load(pp + j);
            d[j] = make_float2(sg * z.x, sg * z.y);
        }
        pp = (const ushort2*)&r1;
#pragma unroll
        for (int j = 0; j < 4; j++) {
            float sg = 1.0f / (1.0f + __expf(-bf2f(gp[4 + j])));
            float2 z = c_load(pp + j);
            d[4 + j] = make_float2(sg * z.x, sg * z.y);
        }
    }
    __syncthreads();
    fft512_r8(B0[li], B1[li], lane, +1.f, TWL);
    {
        const float sc = 1.0f / 512.0f;
        float2* src = &B1[li][9 * lane];
        union { ushort2 u[4]; uint4 q; } o0, o1;
#pragma unroll
        for (int j = 0; j < 4; j++) {
            float2 z = src[j];
            o0.u[j].x = f2bf(z.x * sc); o0.u[j].y = f2bf(z.y * sc);
        }
#pragma unroll
        for (int j = 0; j < 4; j++) {
            float2 z = src[4 + j];
            o1.u[j].x = f2bf(z.x * sc); o1.u[j].y = f2bf(z.y * sc);
        }
        *(uint4*)(s + lane * 8) = o0.q;
        *(uint4*)(s + lane * 8 + 4) = o1.q;
    }
}

// ---------------------------------------------------------------------------
// Column FFT: 16 columns/block, 64 KB LDS + 4 KB twiddle table, in-place
// stages. Fused over 4 buffers (Q/K/V/T); buf==3 writes real to tepReal.
// 512 threads/block; CSW bank swizzle; LDS twiddles.
// ---------------------------------------------------------------------------
__global__ __launch_bounds__(512) void fft8_cols16_c2c4(
    ushort2* __restrict__ data, bf16* __restrict__ tepReal, float sign)
{
    __shared__ float2 B[512][16];
    __shared__ float2 TWL[512];
    const int buf = blockIdx.x >> 10;
    const int rem = blockIdx.x & 1023;
    const int b   = rem >> 5;
    const int c0  = (rem & 31) * 16;
    ushort2* base = data + (long)buf * 8388608 + (long)b * 262144 + c0;
    const int t = threadIdx.x;
    const int lr = t >> 2;      // 0..127
    const int lq = t & 3;
    twl_fill(TWL, t, 512);

#pragma unroll
    for (int it = 0; it < 4; it++) {
        const int row = it * 128 + lr;
        uint4 raw = *(const uint4*)(base + (long)row * 512 + lq * 4);
        const ushort2* pp = (const ushort2*)&raw;
#pragma unroll
        for (int j = 0; j < 4; j++) B[row][CSW(row, lq * 4 + j)] = c_load(pp + j);
    }
    __syncthreads();

    const int col = t & 15;
    const int rb  = t >> 4;     // 0..31
#pragma unroll
    for (int st = 0; st < 3; st++) {
        int n, m, s;
        if (st == 0)      { n = 512; m = 64; s = 1;  }
        else if (st == 1) { n = 64;  m = 8;  s = 8;  }
        else              { n = 8;   m = 1;  s = 64; }
        const int step = (st == 0) ? 1 : 8;   // 512/n (st2 unused: p==0)
        float2 x[2][8];
        int ps[2], qs[2];
#pragma unroll
        for (int i = 0; i < 2; i++) {
            const int role = rb + 32 * i;
            int p, q;
            if (st == 0)      { p = role;      q = 0; }
            else if (st == 1) { p = role >> 3; q = role & 7; }
            else              { p = 0;         q = role; }
            ps[i] = p; qs[i] = q;
#pragma unroll
            for (int r = 0; r < 8; r++) {
                const int rr = q + s * (p + r * m);
                x[i][r] = B[rr][CSW(rr, col)];
            }
        }
        __syncthreads();
#pragma unroll
        for (int i = 0; i < 2; i++) {
            dft8(x[i], sign);
            const int p = ps[i];
            if (p) {
#pragma unroll
                for (int k = 1; k < 8; k++)
                    x[i][k] = cmul(x[i][k], twd(TWL, p * k * step, sign));
            }
#pragma unroll
            for (int k = 0; k < 8; k++) {
                const int rw = qs[i] + s * (8 * p + k);
                B[rw][CSW(rw, col)] = x[i][k];
            }
        }
        __syncthreads();
    }

#pragma unroll
    for (int it = 0; it < 4; it++) {
        const int row = it * 128 + lr;
        union { ushort2 u[4]; uint4 q4; } o;
        union { unsigned short u[4]; ushort4 q4; } orl;
#pragma unroll
        for (int j = 0; j < 4; j++) {
            float2 z = B[row][CSW(row, lq * 4 + j)];
            o.u[j].x = f2bf(z.x); o.u[j].y = f2bf(z.y);
            orl.u[j] = o.u[j].x;
        }
        *(uint4*)(base + (long)row * 512 + lq * 4) = o.q4;
        if (buf == 3)
            *(ushort4*)(tepReal + (long)b * 262144 + (long)row * 512 + c0 + lq * 4) = orl.q4;
    }
}

// Column inverse FFT + abs -> bf16 real (scale 1/512), 16 columns/block,
// 512 threads (same restructure as c2c4).
__global__ __launch_bounds__(512) void fft8_cols16_abs(
    const ushort2* __restrict__ src, bf16* __restrict__ dst)
{
    __shared__ float2 B[512][16];
    __shared__ float2 TWL[512];
    const int b  = blockIdx.x >> 5;
    const int c0 = (blockIdx.x & 31) * 16;
    const ushort2* base = src + (long)b * 262144 + c0;
    const int t = threadIdx.x;
    const int lr = t >> 2;
    const int lq = t & 3;
    twl_fill(TWL, t, 512);

#pragma unroll
    for (int it = 0; it < 4; it++) {
        const int row = it * 128 + lr;
        uint4 raw = *(const uint4*)(base + (long)row * 512 + lq * 4);
        const ushort2* pp = (const ushort2*)&raw;
#pragma unroll
        for (int j = 0; j < 4; j++) B[row][CSW(row, lq * 4 + j)] = c_load(pp + j);
    }
    __syncthreads();

    const int col = t & 15;
    const int rb  = t >> 4;
#pragma unroll
    for (int st = 0; st < 3; st++) {
        int n, m, s;
        if (st == 0)      { n = 512; m = 64; s = 1;  }
        else if (st == 1) { n = 64;  m = 8;  s = 8;  }
        else              { n = 8;   m = 1;  s = 64; }
        const int step = (st == 0) ? 1 : 8;
        float2 x[2][8];
        int ps[2], qs[2];
#pragma unroll
        for (int i = 0; i < 2; i++) {
            const int role = rb + 32 * i;
            int p, q;
            if (st == 0)      { p = role;      q = 0; }
            else if (st == 1) { p = role >> 3; q = role & 7; }
            else              { p = 0;         q = role; }
            ps[i] = p; qs[i] = q;
#pragma unroll
            for (int r = 0; r < 8; r++) {
                const int rr = q + s * (p + r * m);
                x[i][r] = B[rr][CSW(rr, col)];
            }
        }
        __syncthreads();
#pragma unroll
        for (int i = 0; i < 2; i++) {
            dft8(x[i], +1.f);
            const int p = ps[i];
            if (p) {
#pragma unroll
                for (int k = 1; k < 8; k++)
                    x[i][k] = cmul(x[i][k], twd(TWL, p * k * step, +1.f));
            }
#pragma unroll
            for (int k = 0; k < 8; k++) {
                const int rw = qs[i] + s * (8 * p + k);
                B[rw][CSW(rw, col)] = x[i][k];
            }
        }
        __syncthreads();
    }

    const float sc = 1.0f / 512.0f;
#pragma unroll
    for (int it = 0; it < 4; it++) {
        const int row = it * 128 + lr;
        union { unsigned short u[4]; ushort4 q4; } o;
#pragma unroll
        for (int j = 0; j < 4; j++) {
            float2 z = B[row][CSW(row, lq * 4 + j)];
            o.u[j] = f2bf(sqrtf(z.x * z.x + z.y * z.y) * sc);
        }
        *(ushort4*)(dst + (long)b * 262144 + (long)row * 512 + c0 + lq * 4) = o.q4;
    }
}

// ---------------------------------------------------------------------------
// attn v4: 4 (b,c) per block; raw bf16 LDS staging (no pre-normalize pass —
// norms folded into the score loop), LDS ~19.7 KB -> 8 blocks/CU.
// Row pad 68 complex: 272 B stride keeps uint4 alignment and spreads the 8
// head-rows over banks 4h..4h+3 (conflict-free broadcast reads).
// ---------------------------------------------------------------------------
__global__ __launch_bounds__(256) void attn_kernel(
    const ushort2* __restrict__ qf, const ushort2* __restrict__ kf,
    const ushort2* __restrict__ vf, const float* __restrict__ temp,
    bf16* __restrict__ out_f)
{
    __shared__ ushort2 QS[4][8][68];   // raw bf16 q rows
    __shared__ ushort2 KS[4][8][68];   // raw bf16 k rows
    __shared__ float2 ATT[4][8][9];

    const int li = threadIdx.x >> 6, lane = threadIdx.x & 63;
    const int bc = blockIdx.x * 4 + li;
    const long base = (long)bc * 512;

    // stage raw bf16 q,k rows: 2x uint4 (4 complex) per lane per buffer
    {
        const int h1 = lane >> 4, w1 = (lane & 15) * 4;
        uint4 q0 = *(const uint4*)(qf + base + lane * 4);
        uint4 q1 = *(const uint4*)(qf + base + 256 + lane * 4);
        uint4 k0 = *(const uint4*)(kf + base + lane * 4);
        uint4 k1 = *(const uint4*)(kf + base + 256 + lane * 4);
        *(uint4*)&QS[li][h1][w1]     = q0;
        *(uint4*)&QS[li][h1 + 4][w1] = q1;
        *(uint4*)&KS[li][h1][w1]     = k0;
        *(uint4*)&KS[li][h1 + 4][w1] = k1;
    }
    float2 v[8];
#pragma unroll
    for (int h = 0; h < 8; h++)
        v[h] = c_load(vf + base + h * 64 + lane);
    __syncthreads();

    // scores + norms + softmax, fully parallel: lane = (h = lane>>3, g = lane&7)
    // score[h][g] = (q_h . k_g) * temp[h] / (|q_h| |k_g|)  ==  normalized dot
    {
        const int h = lane >> 3, g = lane & 7;
        float ar = 0.f, ai = 0.f, nq = 0.f, nk = 0.f;
#pragma unroll
        for (int w = 0; w < 64; w += 4) {
            uint4 qa = *(const uint4*)&QS[li][h][w];
            uint4 kb = *(const uint4*)&KS[li][g][w];
            const unsigned short* qs = (const unsigned short*)&qa;
            const unsigned short* ks = (const unsigned short*)&kb;
#pragma unroll
            for (int j = 0; j < 4; j++) {
                float qx = bf2f(qs[2 * j]), qy = bf2f(qs[2 * j + 1]);
                float kx = bf2f(ks[2 * j]), ky = bf2f(ks[2 * j + 1]);
                ar += qx * kx - qy * ky;
                ai += qx * ky + qy * kx;
                nq += qx * qx + qy * qy;
                nk += kx * kx + ky * ky;
            }
        }
        const float iq = 1.0f / fmaxf(sqrtf(nq), 1e-12f);
        const float ik = 1.0f / fmaxf(sqrtf(nk), 1e-12f);
        const float s = temp[h] * iq * ik;
        ar *= s; ai *= s;
        // group-of-8 max (offsets 1,2,4 stay within the h-group)
        float mr = ar, mi = ai;
#pragma unroll
        for (int o = 1; o < 8; o <<= 1) {
            mr = fmaxf(mr, __shfl_xor(mr, o, 64));
            mi = fmaxf(mi, __shfl_xor(mi, o, 64));
        }
        float er = __expf(ar - mr), ei = __expf(ai - mi);
        float sr = er, si = ei;
#pragma unroll
        for (int o = 1; o < 8; o <<= 1) {
            sr += __shfl_xor(sr, o, 64);
            si += __shfl_xor(si, o, 64);
        }
        ATT[li][h][g] = make_float2(er / sr, ei / si);
    }
    __syncthreads();

    float2 o[8];
#pragma unroll
    for (int h = 0; h < 8; h++) {
        float orr = 0.f, oi = 0.f;
#pragma unroll
        for (int g = 0; g < 8; g++) {
            float2 a = ATT[li][h][g], b = v[g];
            orr += a.x * b.x - a.y * b.y;
            oi  += a.x * b.y + a.y * b.x;
        }
        o[h] = make_float2(orr, oi);
    }

#pragma unroll
    for (int m = 32; m >= 1; m >>= 1) {
        float ang = (FFT_PI / (float)m) * (float)(lane & (m - 1));
        float sw, cw;
        __sincosf(ang, &sw, &cw);
        const bool low = (lane & m) == 0;
#pragma unroll
        for (int h = 0; h < 8; h++) {
            float px = __shfl_xor(o[h].x, m, 64);
            float py = __shfl_xor(o[h].y, m, 64);
            float nx, ny;
            if (low) {
                nx = o[h].x + px;
                ny = o[h].y + py;
            } else {
                float dx = px - o[h].x;
                float dy = py - o[h].y;
                nx = dx * cw - dy * sw;
                ny = dx * sw + dy * cw;
            }
            o[h].x = nx; o[h].y = ny;
        }
    }
    const int wr = brev6(lane);

    const float r2 = 0.70710678118654752f;
    const float W8x[8] = {1.f,  r2, 0.f, -r2, -1.f, -r2,  0.f,  r2};
    const float W8y[8] = {0.f,  r2, 1.f,  r2,  0.f, -r2, -1.f, -r2};
    unsigned short* stg = (unsigned short*)&QS[li][0][0];
#pragma unroll
    for (int kh = 0; kh < 8; kh++) {
        float sr = 0.f, si = 0.f;
#pragma unroll
        for (int n = 0; n < 8; n++) {
            const int idx = (n * kh) & 7;
            float wx = W8x[idx], wy = W8y[idx];
            sr += o[n].x * wx - o[n].y * wy;
            si += o[n].x * wy + o[n].y * wx;
        }
        stg[kh * 64 + wr] = f2bf(sqrtf(sr * sr + si * si) * (1.0f / 512.0f));
    }
    __syncthreads();
    uint4 ov = *(uint4*)(stg + lane * 8);
    *(uint4*)((unsigned short*)out_f + base + lane * 8) = ov;
}

// ---------------------------------------------------------------------------
extern "C" void kernel_launch(void* const* d_in, const int* in_sizes, int n_in,
                              void* d_out, int out_size, void* d_ws, size_t ws_size,
                              hipStream_t stream)
{
    const float* x     = (const float*)d_in[0];
    const float* W_in  = (const float*)d_in[1];
    const float* b_in  = (const float*)d_in[2];
    const float* W_q   = (const float*)d_in[3];
    const float* b_q   = (const float*)d_in[4];
    const float* W_k   = (const float*)d_in[5];
    const float* b_k   = (const float*)d_in[6];
    const float* W_v   = (const float*)d_in[7];
    const float* b_v   = (const float*)d_in[8];
    const float* temp  = (const float*)d_in[9];
    const float* W1a   = (const float*)d_in[10];
    const float* b1a   = (const float*)d_in[11];
    const float* gam   = (const float*)d_in[12];
    const float* bet   = (const float*)d_in[13];
    const float* mea   = (const float*)d_in[14];
    const float* var   = (const float*)d_in[15];
    const float* W1b   = (const float*)d_in[16];
    const float* b1b   = (const float*)d_in[17];
    const float* W_out = (const float*)d_in[18];
    const float* b_out = (const float*)d_in[19];

    char* wsb = (char*)d_ws;
    const long MB = 1024 * 1024;
    bf16*    conv2b  = (bf16*)wsb;
    bf16*    tepReal = (bf16*)(wsb + 16 * MB);
    ushort2* Qb    = (ushort2*)(wsb + 32 * MB);
    ushort2* Kb    = (ushort2*)(wsb + 64 * MB);
    ushort2* Vb    = (ushort2*)(wsb + 96 * MB);
    ushort2* Tb    = (ushort2*)(wsb + 128 * MB);
    bf16*    Wt    = (bf16*)(wsb + 160 * MB);
    bf16* WT_in  = Wt;
    bf16* WT_q   = Wt + 262144;
    bf16* WT_1a  = Wt + 4 * 262144;
    bf16* WT_1b  = Wt + 5 * 262144;
    bf16* WT_out = Wt + 6 * 262144;
    bf16* outF = (bf16*)Qb;
    bf16* g1b  = (bf16*)Kb;
    bf16* outL = (bf16*)Kb;
    bf16* g2b  = (bf16*)Vb;

    const dim3 ggrid(4, 128), gblk(256);
    const int BIG = 1 << 30;
    const int RB = 4096;

    transpose_cvt_all<<<dim3(16, 32, 7), dim3(32, 8), 0, stream>>>(
        W_in, W_q, W_k, W_v, W1a, W1b, W_out, Wt);

    // 1. conv2 = x @ W_in + b_in -> bf16  (f32 A, manual staging)
    mfma_gemm<<<ggrid, gblk, 0, stream>>>(
        x, x, 1, 512, BIG, WT_in, 512, b_in, nullptr, nullptr,
        conv2b, nullptr, nullptr, BIG, 1, 512, 512,
        nullptr, nullptr, nullptr, nullptr);

    // 2. fused q/k/v projections (async staging)
    mfma_gemm<<<dim3(12, 128), gblk, 0, stream>>>(
        conv2b, conv2b, 0, 512, BIG, WT_q, 512, b_q, b_k, b_v,
        Qb, Kb, Vb, 512, 2, 512, 512,
        nullptr, nullptr, nullptr, nullptr);

    // 3. all row FFTs (Q/K/V c2c + tep r2c) in one dispatch
    fft8_rows_all<<<4 * RB, 256, 0, stream>>>(Qb, conv2b, Tb);

    // 4. col FFTs: Q,K,V,T fused, 16 cols/block, 512 threads
    fft8_cols16_c2c4<<<4096, 512, 0, stream>>>(Qb, tepReal, -1.f);

    // 5. attention -> out_f bf16 over Qb
    attn_kernel<<<RB, 256, 0, stream>>>(Qb, Kb, Vb, temp, outF);

    // 6. g1 = BN_ReLU(tepReal @ W1a + b1a) -> bf16
    mfma_gemm<<<ggrid, gblk, 0, stream>>>(
        tepReal, tepReal, 0, 512, BIG, WT_1a, 512, b1a, nullptr, nullptr,
        g1b, nullptr, nullptr, BIG, 3, 512, 512,
        mea, var, gam, bet);

    // 7. g2 = g1 @ W1b + b1b -> bf16
    mfma_gemm<<<ggrid, gblk, 0, stream>>>(
        g1b, g1b, 0, 512, BIG, WT_1b, 512, b1b, nullptr, nullptr,
        g2b, nullptr, nullptr, BIG, 1, 512, 512,
        nullptr, nullptr, nullptr, nullptr);

    // 8. gated ifft2 + abs -> out_l bf16 (over Kb)
    fft8_rows_gated<<<RB, 256, 0, stream>>>(g2b, Tb);
    fft8_cols16_abs<<<1024, 512, 0, stream>>>(Tb, outL);

    // 9. d_out = [out_f | out_l] @ W_out + b_out + conv2 (K=1024, fused residual)
    mfma_gemm<<<ggrid, gblk, 0, stream>>>(
        outF, outL, 0, 512, 512, WT_out, 1024, b_out, nullptr, nullptr,
        d_out, nullptr, nullptr, BIG, 4, 512, 1024,
        (const float*)conv2b, nullptr, nullptr, nullptr);
}